// Round 19
// baseline (237.091 us; speedup 1.0000x reference)
//
#include <hip/hip_runtime.h>
#include <hip/hip_bf16.h>

#define B_ 32
#define C_ 256
#define N_ 1024
#define D_ 64

typedef __attribute__((ext_vector_type(8))) short bf16x8;
typedef __attribute__((ext_vector_type(4))) float f32x4;

// key = (monotone(v) << 10) | (1023 - m): larger key <=> larger v, tie -> smaller m.
__device__ __forceinline__ unsigned long long pack_key(float v, int m) {
    const unsigned int bits = __float_as_uint(v);
    const unsigned int mono = (bits & 0x80000000u) ? ~bits : (bits | 0x80000000u);
    return ((unsigned long long)mono << 10) | (unsigned long long)(1023 - m);
}

template <int CTRL>
__device__ __forceinline__ float dpp_mov_f(float x) {
    return __int_as_float(__builtin_amdgcn_update_dpp(
        0, __float_as_int(x), CTRL, 0xF, 0xF, true));
}
#define DPP_QUAD_XOR1   0xB1
#define DPP_QUAD_XOR2   0x4E
#define DPP_HALF_MIRROR 0x141
#define DPP_ROW_ROR8    0x128

template <int CTRL>
__device__ __forceinline__ unsigned long long dpp_max_u64(unsigned long long k) {
    const unsigned int lo = (unsigned int)k;
    const unsigned int hi = (unsigned int)(k >> 32);
    const unsigned int plo = (unsigned int)__builtin_amdgcn_update_dpp(0, (int)lo, CTRL, 0xF, 0xF, true);
    const unsigned int phi = (unsigned int)__builtin_amdgcn_update_dpp(0, (int)hi, CTRL, 0xF, 0xF, true);
    const unsigned long long p = ((unsigned long long)phi << 32) | plo;
    return p > k ? p : k;
}

// Packed dual FMA: lo: a.x += q_sel * k.x ; hi: a.y += q_sel * k.y
// q_sel = qp.x (OS=0) or qp.y (OS=1); qp is WAVE-UNIFORM -> SGPR pair src0.
// Each component is an IEEE round-to-nearest FMA -> chains stay bit-exact.
template <int OS>
__device__ __forceinline__ float2 pkb(float2 qp, float2 k, float2 a) {
    float2 d;
    if (OS == 0)
        asm("v_pk_fma_f32 %0, %1, %2, %3 op_sel:[0,0,0] op_sel_hi:[0,1,1]"
            : "=v"(d) : "s"(qp), "v"(k), "v"(a));
    else
        asm("v_pk_fma_f32 %0, %1, %2, %3 op_sel:[1,0,0] op_sel_hi:[1,1,1]"
            : "=v"(d) : "s"(qp), "v"(k), "v"(a));
    return d;
}

__device__ __forceinline__ unsigned short f2bf(float f) {
    __hip_bfloat16 h = __float2bfloat16(f);
    return *(unsigned short*)&h;
}

// ---------------------------------------------------------------------------
// Fused kernel A: blocks 0..255 = wt (+wvb) transpose; blocks 256..2303 = xt.
// ---------------------------------------------------------------------------
__global__ __launch_bounds__(256) void prep_kernel(
    const float* __restrict__ x,
    const float* __restrict__ wq, const float* __restrict__ wk,
    const float* __restrict__ wv, float* __restrict__ wt,
    unsigned short* __restrict__ wvb, unsigned short* __restrict__ xtb,
    int mfma_path)
{
    __shared__ __align__(16) float tl[64][65];
    const int bid = blockIdx.x;
    const int t = threadIdx.x;

    if (bid < 256) {
        const int c = bid;
        for (int r = t; r < 384; r += 256) {
            float v;
            if      (r < 64)  v = wq[(size_t)r * C_ + c];
            else if (r < 128) v = wk[(size_t)(r - 64) * C_ + c];
            else              v = wv[(size_t)(r - 128) * C_ + c];
            wt[(size_t)c * 384 + r] = v;
        }
        if (mfma_path) wvb[(size_t)c * C_ + t] = f2bf(wv[(size_t)c * C_ + t]);
        return;
    }
    if (!mfma_path) return;

    const int lid = bid - 256;
    const int b     = (lid & 7) + 8 * (lid >> 9);
    const int inner = (lid >> 3) & 63;
    const int nt    = inner & 15;
    const int ct    = inner >> 4;
    const int n0 = nt * 64, c0 = ct * 64;

    const float* xb = x + (size_t)b * C_ * N_;
    #pragma unroll
    for (int p = 0; p < 4; ++p) {
        const int cl = (t >> 4) + p * 16;
        const int nl = (t & 15) * 4;
        *(float4*)&tl[cl][nl] = *(const float4*)&xb[(size_t)(c0 + cl) * N_ + n0 + nl];
    }
    __syncthreads();

    unsigned short* dstb = xtb + ((size_t)b * N_) * C_;
    #pragma unroll
    for (int p = 0; p < 4; ++p) {
        const int nl = (t >> 4) + p * 16;
        const int cl = (t & 15) * 4;
        ushort4 o;
        o.x = f2bf(tl[cl + 0][nl]);
        o.y = f2bf(tl[cl + 1][nl]);
        o.z = f2bf(tl[cl + 2][nl]);
        o.w = f2bf(tl[cl + 3][nl]);
        *(ushort4*)&dstb[(size_t)(n0 + nl) * C_ + c0 + cl] = o;
    }
}

// ---------------------------------------------------------------------------
// Fused kernel B: blocks 0..1023 = q,k projection (bit-exact, pk_fma);
//                 blocks 1024..3071 = V projection via bf16 MFMA.
// ---------------------------------------------------------------------------
__global__ __launch_bounds__(256) void proj_kernel(
    const float* __restrict__ x, const float* __restrict__ wt,
    const float* __restrict__ bq, const float* __restrict__ bk,
    float* __restrict__ qk,
    const unsigned short* __restrict__ xtb, const unsigned short* __restrict__ wvb,
    const float* __restrict__ bv, float* __restrict__ vt)
{
    const int bid = blockIdx.x;
    const int t = threadIdx.x;
    const int lane = t & 63;

    if (bid < 1024) {
        // ---- q,k: ascending-c fmaf chain via packed dual-FMA (bit-exact) ----
        const int lid = bid;
        const int b     = (lid & 7) + 8 * (lid >> 8);
        const int inner = (lid >> 3) & 31;
        const int rg    = inner & 7;
        const int nt    = inner >> 3;
        const int r0 = rg * 16;
        const int n0 = nt * 256;
        const int wu = __builtin_amdgcn_readfirstlane(t >> 6);
        const int rw = r0 + wu * 4;

        float2 acc2[4][2];
        #pragma unroll
        for (int i = 0; i < 4; ++i) {
            acc2[i][0] = make_float2(0.f, 0.f);
            acc2[i][1] = make_float2(0.f, 0.f);
        }

        const float* xp = x + (size_t)b * C_ * N_ + n0 + lane * 4;
        const float* wp = wt + rw;

        #pragma unroll 8
        for (int c = 0; c < C_; ++c) {
            const float2 x01 = *(const float2*)(xp + (size_t)c * N_);
            const float2 x23 = *(const float2*)(xp + (size_t)c * N_ + 2);
            const float4 w4 = *(const float4*)(wp + (size_t)c * 384);   // uniform s_load
            float2 wA; wA.x = w4.x; wA.y = w4.y;
            float2 wB; wB.x = w4.z; wB.y = w4.w;
            acc2[0][0] = pkb<0>(wA, x01, acc2[0][0]); acc2[0][1] = pkb<0>(wA, x23, acc2[0][1]);
            acc2[1][0] = pkb<1>(wA, x01, acc2[1][0]); acc2[1][1] = pkb<1>(wA, x23, acc2[1][1]);
            acc2[2][0] = pkb<0>(wB, x01, acc2[2][0]); acc2[2][1] = pkb<0>(wB, x23, acc2[2][1]);
            acc2[3][0] = pkb<1>(wB, x01, acc2[3][0]); acc2[3][1] = pkb<1>(wB, x23, acc2[3][1]);
        }

        #pragma unroll
        for (int i = 0; i < 4; ++i) {
            const int R = rw + i;
            const float bb = (R < 64) ? bq[R] : bk[R - 64];
            float4 o;
            o.x = acc2[i][0].x + bb; o.y = acc2[i][0].y + bb;
            o.z = acc2[i][1].x + bb; o.w = acc2[i][1].y + bb;
            *(float4*)&qk[((size_t)b * 128 + R) * N_ + n0 + lane * 4] = o;
        }
    } else {
        // ---- V via bf16 MFMA (continuous path, 2% tolerance) ----
        const int lid = bid - 1024;
        const int b     = (lid & 7) + 8 * (lid >> 9);
        const int inner = (lid >> 3) & 63;
        const int nb    = inner & 15;
        const int eb    = inner >> 4;
        const int w  = t >> 6;
        const int n_base = nb * 64 + (w & 1) * 32;
        const int e_base = eb * 64 + (w >> 1) * 32;

        const int l16  = lane & 15;
        const int koff = 8 * (lane >> 4);

        f32x4 acc[2][2];
        #pragma unroll
        for (int i = 0; i < 2; ++i)
            #pragma unroll
            for (int j = 0; j < 2; ++j) acc[i][j] = (f32x4)(0.f);

        const unsigned short* ab = wvb + (size_t)(e_base + l16) * C_ + koff;
        const unsigned short* bb = xtb + ((size_t)b * N_ + n_base + l16) * C_ + koff;

        #pragma unroll
        for (int kk = 0; kk < 8; ++kk) {
            const int c0 = kk * 32;
            bf16x8 a0 = *(const bf16x8*)(ab + c0);
            bf16x8 a1 = *(const bf16x8*)(ab + 16 * C_ + c0);
            bf16x8 b0 = *(const bf16x8*)(bb + c0);
            bf16x8 b1 = *(const bf16x8*)(bb + 16 * C_ + c0);
            acc[0][0] = __builtin_amdgcn_mfma_f32_16x16x32_bf16(a0, b0, acc[0][0], 0, 0, 0);
            acc[0][1] = __builtin_amdgcn_mfma_f32_16x16x32_bf16(a0, b1, acc[0][1], 0, 0, 0);
            acc[1][0] = __builtin_amdgcn_mfma_f32_16x16x32_bf16(a1, b0, acc[1][0], 0, 0, 0);
            acc[1][1] = __builtin_amdgcn_mfma_f32_16x16x32_bf16(a1, b1, acc[1][1], 0, 0, 0);
        }

        const int col  = lane & 15;
        const int row0 = (lane >> 4) * 4;
        #pragma unroll
        for (int i = 0; i < 2; ++i) {
            const int e0 = e_base + i * 16 + row0;
            const float4 bvv = *(const float4*)&bv[e0];
            #pragma unroll
            for (int j = 0; j < 2; ++j) {
                const int n = n_base + j * 16 + col;
                float4 o;
                o.x = acc[i][j][0] + bvv.x; o.y = acc[i][j][1] + bvv.y;
                o.z = acc[i][j][2] + bvv.z; o.w = acc[i][j][3] + bvv.w;
                *(float4*)&vt[((size_t)b * N_ + n) * C_ + e0] = o;
            }
        }
    }
}

// ---------------------------------------------------------------------------
// Fallback: full projection (r16 scalar version) if workspace too small.
// ---------------------------------------------------------------------------
__global__ __launch_bounds__(256) void proj_full_kernel(
    const float* __restrict__ x, const float* __restrict__ wt,
    const float* __restrict__ bq, const float* __restrict__ bk,
    const float* __restrict__ bv,
    float* __restrict__ qk, float* __restrict__ vt)
{
    const int lid = blockIdx.x;
    const int b     = (lid & 7) + 8 * (lid / 384);
    const int inner = (lid >> 3) % 48;
    const int rg    = inner % 12;
    const int nt    = inner / 12;
    const int r0 = rg * 32;
    const int n0 = nt * 256;
    const int lane = threadIdx.x & 63;
    const int wu = __builtin_amdgcn_readfirstlane(threadIdx.x >> 6);
    const int rw = r0 + wu * 8;

    float acc[8][4];
    #pragma unroll
    for (int i = 0; i < 8; ++i)
        #pragma unroll
        for (int j = 0; j < 4; ++j) acc[i][j] = 0.f;

    const float* xp = x + (size_t)b * C_ * N_ + n0 + lane * 4;
    const float* wp = wt + rw;

    #pragma unroll 8
    for (int c = 0; c < C_; ++c) {
        const float4 xv = *(const float4*)(xp + (size_t)c * N_);
        const float* wr = wp + (size_t)c * 384;
        const float4 w0 = *(const float4*)(wr);
        const float4 w1 = *(const float4*)(wr + 4);
        const float wv8[8] = { w0.x, w0.y, w0.z, w0.w, w1.x, w1.y, w1.z, w1.w };
        #pragma unroll
        for (int i = 0; i < 8; ++i) {
            acc[i][0] = fmaf(wv8[i], xv.x, acc[i][0]);
            acc[i][1] = fmaf(wv8[i], xv.y, acc[i][1]);
            acc[i][2] = fmaf(wv8[i], xv.z, acc[i][2]);
            acc[i][3] = fmaf(wv8[i], xv.w, acc[i][3]);
        }
    }

    if (r0 < 128) {
        #pragma unroll
        for (int i = 0; i < 8; ++i) {
            const int R = rw + i;
            const float bb = (R < 64) ? bq[R] : bk[R - 64];
            float4 o; o.x = acc[i][0]+bb; o.y = acc[i][1]+bb; o.z = acc[i][2]+bb; o.w = acc[i][3]+bb;
            *(float4*)&qk[((size_t)b * 128 + R) * N_ + n0 + lane * 4] = o;
        }
    } else {
        const int e0 = rw - 128;
        float be[8];
        #pragma unroll
        for (int i = 0; i < 8; ++i) be[i] = bv[e0 + i];
        #pragma unroll
        for (int j = 0; j < 4; ++j) {
            const int n = n0 + lane * 4 + j;
            float* dst = &vt[((size_t)b * N_ + n) * C_ + e0];
            float4 o0; o0.x = acc[0][j]+be[0]; o0.y = acc[1][j]+be[1]; o0.z = acc[2][j]+be[2]; o0.w = acc[3][j]+be[3];
            float4 o1; o1.x = acc[4][j]+be[4]; o1.y = acc[5][j]+be[5]; o1.z = acc[6][j]+be[6]; o1.w = acc[7][j]+be[7];
            *(float4*)dst       = o0;
            *(float4*)(dst + 4) = o1;
        }
    }
}

// ---------------------------------------------------------------------------
// Kernel 3: attention. r18 structure; sim loop now packed dual-FMA (bit-exact
// per-component IEEE FMA, same ascending-d chain). Stage A DPP threshold,
// cap-48 compaction + exact fallback; stage B split-half DPP extraction.
// ---------------------------------------------------------------------------
__global__ __launch_bounds__(512) void attn_kernel(
    const float* __restrict__ x,
    const float* __restrict__ qk,
    const float* __restrict__ vt,
    const float* __restrict__ scale,
    float* __restrict__ out)
{
    const int lid = blockIdx.x;
    const int b  = (lid & 7) + 8 * (lid >> 9);
    const int n0 = ((lid >> 3) & 63) * 16;
    const int t  = threadIdx.x;
    const int lane = t & 63;
    const int w  = t >> 6;
    const int ms = w & 3;
    const int rg = __builtin_amdgcn_readfirstlane(t >> 8);

    __shared__ unsigned long long cand[16][196];
    __shared__ int   ccnt[16][4];

    const int m_base = ms * 256 + lane * 4;

    float2 A01[8], A23[8];
    #pragma unroll
    for (int r = 0; r < 8; ++r) {
        A01[r] = make_float2(0.f, 0.f);
        A23[r] = make_float2(0.f, 0.f);
    }

    const float* kb = qk + ((size_t)b * 128 + 64) * N_ + m_base;
    const float* qb = qk + (size_t)b * 128 * N_ + n0 + rg * 8;

    #pragma unroll 2
    for (int d0 = 0; d0 < D_; d0 += 4) {
        float2 k01[4], k23[4];
        #pragma unroll
        for (int dd = 0; dd < 4; ++dd) {
            k01[dd] = *(const float2*)&kb[(size_t)(d0+dd) * N_];
            k23[dd] = *(const float2*)&kb[(size_t)(d0+dd) * N_ + 2];
        }
        #pragma unroll
        for (int dd = 0; dd < 4; ++dd) {
            const float4 qv0 = *(const float4*)&qb[(size_t)(d0+dd) * N_ + 0];  // rows 0..3
            const float4 qv1 = *(const float4*)&qb[(size_t)(d0+dd) * N_ + 4];  // rows 4..7
            float2 qpA; qpA.x = qv0.x; qpA.y = qv0.y;
            float2 qpB; qpB.x = qv0.z; qpB.y = qv0.w;
            float2 qpC; qpC.x = qv1.x; qpC.y = qv1.y;
            float2 qpD; qpD.x = qv1.z; qpD.y = qv1.w;
            A01[0] = pkb<0>(qpA, k01[dd], A01[0]); A23[0] = pkb<0>(qpA, k23[dd], A23[0]);
            A01[1] = pkb<1>(qpA, k01[dd], A01[1]); A23[1] = pkb<1>(qpA, k23[dd], A23[1]);
            A01[2] = pkb<0>(qpB, k01[dd], A01[2]); A23[2] = pkb<0>(qpB, k23[dd], A23[2]);
            A01[3] = pkb<1>(qpB, k01[dd], A01[3]); A23[3] = pkb<1>(qpB, k23[dd], A23[3]);
            A01[4] = pkb<0>(qpC, k01[dd], A01[4]); A23[4] = pkb<0>(qpC, k23[dd], A23[4]);
            A01[5] = pkb<1>(qpC, k01[dd], A01[5]); A23[5] = pkb<1>(qpC, k23[dd], A23[5]);
            A01[6] = pkb<0>(qpD, k01[dd], A01[6]); A23[6] = pkb<0>(qpD, k23[dd], A23[6]);
            A01[7] = pkb<1>(qpD, k01[dd], A01[7]); A23[7] = pkb<1>(qpD, k23[dd], A23[7]);
        }
    }

    // ---- stage A: per-slice threshold filter + compaction (exact superset) ----
    const unsigned long long lt = (1ull << lane) - 1ull;
    #pragma unroll
    for (int r = 0; r < 8; ++r) {
        const int ri = rg * 8 + r;
        const int nrow = n0 + ri;
        float t0 = A01[r].x, t1 = A01[r].y, t2 = A23[r].x, t3 = A23[r].y;
        const int dj = nrow - m_base;
        if      (dj == 0) t0 = -1.0e9f;
        else if (dj == 1) t1 = -1.0e9f;
        else if (dj == 2) t2 = -1.0e9f;
        else if (dj == 3) t3 = -1.0e9f;

        float lm = fmaxf(fmaxf(t0, t1), fmaxf(t2, t3));
        lm = fmaxf(lm, dpp_mov_f<DPP_QUAD_XOR1>(lm));
        lm = fmaxf(lm, dpp_mov_f<DPP_QUAD_XOR2>(lm));
        lm = fmaxf(lm, dpp_mov_f<DPP_HALF_MIRROR>(lm));
        float Th = fminf(lm, dpp_mov_f<DPP_ROW_ROR8>(lm));
        Th = fminf(Th, __shfl_xor(Th, 16));
        Th = fminf(Th, __shfl_xor(Th, 32));

        int cnt = 0;
        {
            const bool p = (t0 >= Th);
            const unsigned long long msk = __ballot(p);
            const int pos = cnt + (int)__popcll(msk & lt);
            if (p && pos < 48) cand[ri][ms * 49 + pos] = pack_key(t0, m_base + 0);
            cnt += (int)__popcll(msk);
        }
        {
            const bool p = (t1 >= Th);
            const unsigned long long msk = __ballot(p);
            const int pos = cnt + (int)__popcll(msk & lt);
            if (p && pos < 48) cand[ri][ms * 49 + pos] = pack_key(t1, m_base + 1);
            cnt += (int)__popcll(msk);
        }
        {
            const bool p = (t2 >= Th);
            const unsigned long long msk = __ballot(p);
            const int pos = cnt + (int)__popcll(msk & lt);
            if (p && pos < 48) cand[ri][ms * 49 + pos] = pack_key(t2, m_base + 2);
            cnt += (int)__popcll(msk);
        }
        {
            const bool p = (t3 >= Th);
            const unsigned long long msk = __ballot(p);
            const int pos = cnt + (int)__popcll(msk & lt);
            if (p && pos < 48) cand[ri][ms * 49 + pos] = pack_key(t3, m_base + 3);
            cnt += (int)__popcll(msk);
        }

        if (cnt > 48) {   // exact fallback: slice top-8 via 8 extraction rounds
            unsigned long long K0 = pack_key(t0, m_base + 0);
            unsigned long long K1 = pack_key(t1, m_base + 1);
            unsigned long long K2 = pack_key(t2, m_base + 2);
            unsigned long long K3 = pack_key(t3, m_base + 3);
            #pragma unroll 1
            for (int round = 0; round < 8; ++round) {
                unsigned long long kl = K0 > K1 ? K0 : K1;
                kl = K2 > kl ? K2 : kl;
                kl = K3 > kl ? K3 : kl;
                #pragma unroll
                for (int off = 32; off >= 1; off >>= 1) {
                    const unsigned long long ks = __shfl_xor(kl, off);
                    if (ks > kl) kl = ks;
                }
                if (lane == 0) cand[ri][ms * 49 + round] = kl;
                if      (K0 == kl) K0 = 0ull;
                else if (K1 == kl) K1 = 0ull;
                else if (K2 == kl) K2 = 0ull;
                else if (K3 == kl) K3 = 0ull;
            }
            cnt = 8;
        }
        if (lane == 0) ccnt[ri][ms] = cnt;
    }
    __syncthreads();

    // ---- stage B: split-half extraction (2 rows concurrently per wave) ----
    {
        const int half = lane >> 5;
        const int r    = w * 2 + half;
        const int l5   = lane & 31;

        unsigned long long k[6];
        #pragma unroll
        for (int s = 0; s < 4; ++s)
            k[s] = (l5 < ccnt[r][s]) ? cand[r][s * 49 + l5] : 0ull;
        #pragma unroll
        for (int j = 0; j < 2; ++j) {
            const int g   = l5 + 32 * j;
            const int s   = g >> 4;
            const int pos = 32 + (g & 15);
            k[4 + j] = (pos < ccnt[r][s]) ? cand[r][s * 49 + pos] : 0ull;
        }

        #pragma unroll 1
        for (int round = 0; round < 8; ++round) {
            unsigned long long km = k[0];
            #pragma unroll
            for (int q = 1; q < 6; ++q) km = k[q] > km ? k[q] : km;
            km = dpp_max_u64<DPP_QUAD_XOR1>(km);
            km = dpp_max_u64<DPP_QUAD_XOR2>(km);
            km = dpp_max_u64<DPP_HALF_MIRROR>(km);
            km = dpp_max_u64<DPP_ROW_ROR8>(km);
            { const unsigned long long p = __shfl_xor(km, 16); km = p > km ? p : km; }
            if (l5 == 0) cand[r][188 + round] = km;
            #pragma unroll
            for (int q = 0; q < 6; ++q) if (k[q] == km) k[q] = 0ull;
        }
    }

    // ---- decode winners + softmax + batched V gathers (all 64 lanes/row) ----
    const float* vtb = vt + (size_t)b * N_ * C_;
    #pragma unroll 1
    for (int rr = 0; rr < 2; ++rr) {
        const int r = w * 2 + rr;
        float ev[8]; unsigned int mi[8];
        float S = 0.f, vmax = 0.f;
        #pragma unroll
        for (int j = 0; j < 8; ++j) {
            const unsigned long long km = cand[r][188 + j];
            const unsigned int mono = (unsigned int)(km >> 10);
            mi[j] = 1023u - ((unsigned int)km & 1023u);
            const unsigned int bits = (mono & 0x80000000u) ? (mono & 0x7FFFFFFFu) : ~mono;
            const float vraw = __uint_as_float(bits);
            if (j == 0) vmax = vraw;
            const float e = __expf((vraw - vmax) * 0.125f);
            S += e;
            ev[j] = e;
        }

        float4 o = make_float4(0.f, 0.f, 0.f, 0.f);
        #pragma unroll
        for (int j = 0; j < 8; ++j) {
            const float4 vv = *(const float4*)&vtb[(size_t)mi[j] * C_ + lane * 4];
            o.x += ev[j] * vv.x; o.y += ev[j] * vv.y;
            o.z += ev[j] * vv.z; o.w += ev[j] * vv.w;
        }
        const float inv = 1.f / S;
        float* orow = (float*)&cand[r][0];
        *(float4*)&orow[lane * 4] = make_float4(o.x*inv, o.y*inv, o.z*inv, o.w*inv);
    }
    __syncthreads();

    // ---- residual + (b, c, n) write ----
    const float sc = scale[0];
    const float* xb = x + (size_t)b * C_ * N_;
    float* ob = out + (size_t)b * C_ * N_;
    const int nl = t & 15;
    const int cg = t >> 4;
    const float* orow = (const float*)&cand[nl][0];
    #pragma unroll
    for (int i = 0; i < 8; ++i) {
        const int cc = i * 32 + cg;
        const size_t gi = (size_t)cc * N_ + n0 + nl;
        ob[gi] = xb[gi] + sc * orow[cc];
    }
}

extern "C" void kernel_launch(void* const* d_in, const int* in_sizes, int n_in,
                              void* d_out, int out_size, void* d_ws, size_t ws_size,
                              hipStream_t stream) {
    const float* x     = (const float*)d_in[0];
    const float* wq    = (const float*)d_in[1];
    const float* bq    = (const float*)d_in[2];
    const float* wk    = (const float*)d_in[3];
    const float* bk    = (const float*)d_in[4];
    const float* wv    = (const float*)d_in[5];
    const float* bv    = (const float*)d_in[6];
    const float* scale = (const float*)d_in[7];
    float* out = (float*)d_out;

    float* qk = (float*)d_ws;                         // 16.78 MB
    float* vt = qk + (size_t)B_ * 128 * N_;           // 33.55 MB
    float* wt = vt + (size_t)B_ * N_ * C_;            //  0.39 MB
    unsigned short* wvb = (unsigned short*)(wt + 256 * 384);   // 0.13 MB
    unsigned short* xtb = wvb + (size_t)C_ * C_;               // 16.78 MB

    const size_t needed = ((char*)(xtb + (size_t)B_ * N_ * C_)) - (char*)d_ws;
    const int mfma_path = (ws_size >= needed) ? 1 : 0;

    prep_kernel<<<dim3(256 + 2048), 256, 0, stream>>>(x, wq, wk, wv, wt, wvb, xtb, mfma_path);
    if (mfma_path) {
        proj_kernel<<<dim3(1024 + 2048), 256, 0, stream>>>(x, wt, bq, bk, qk, xtb, wvb, bv, vt);
    } else {
        proj_full_kernel<<<dim3(1536), 256, 0, stream>>>(x, wt, bq, bk, bv, qk, vt);
    }
    attn_kernel<<<dim3(2048), 512, 0, stream>>>(x, qk, vt, scale, out);
}

// Round 20
// 177.935 us; speedup vs baseline: 1.3325x; 1.3325x over previous
//
#include <hip/hip_runtime.h>
#include <hip/hip_bf16.h>

#define B_ 32
#define C_ 256
#define N_ 1024
#define D_ 64

typedef __attribute__((ext_vector_type(8))) short bf16x8;
typedef __attribute__((ext_vector_type(4))) float f32x4;

// key = (monotone(v) << 10) | (1023 - m): larger key <=> larger v, tie -> smaller m.
__device__ __forceinline__ unsigned long long pack_key(float v, int m) {
    const unsigned int bits = __float_as_uint(v);
    const unsigned int mono = (bits & 0x80000000u) ? ~bits : (bits | 0x80000000u);
    return ((unsigned long long)mono << 10) | (unsigned long long)(1023 - m);
}

// DPP cross-lane move (VALU pipe, not DS). ctrl must be an immediate -> template.
template <int CTRL>
__device__ __forceinline__ float dpp_mov_f(float x) {
    return __int_as_float(__builtin_amdgcn_update_dpp(
        0, __float_as_int(x), CTRL, 0xF, 0xF, true));
}
#define DPP_QUAD_XOR1   0xB1
#define DPP_QUAD_XOR2   0x4E
#define DPP_HALF_MIRROR 0x141
#define DPP_ROW_ROR8    0x128

// u64 max with DPP-permuted partner (xor1/2/4/8 patterns; VALU only).
template <int CTRL>
__device__ __forceinline__ unsigned long long dpp_max_u64(unsigned long long k) {
    const unsigned int lo = (unsigned int)k;
    const unsigned int hi = (unsigned int)(k >> 32);
    const unsigned int plo = (unsigned int)__builtin_amdgcn_update_dpp(0, (int)lo, CTRL, 0xF, 0xF, true);
    const unsigned int phi = (unsigned int)__builtin_amdgcn_update_dpp(0, (int)hi, CTRL, 0xF, 0xF, true);
    const unsigned long long p = ((unsigned long long)phi << 32) | plo;
    return p > k ? p : k;
}

__device__ __forceinline__ unsigned short f2bf(float f) {
    __hip_bfloat16 h = __float2bfloat16(f);
    return *(unsigned short*)&h;
}

// ---------------------------------------------------------------------------
// Kernel 0: wt[c][384] transpose of [wq;wk;wv] (fp32, for exact qk path);
// threads >=128 also emit wvb = bf16 copy of wv (row-major, for MFMA A-frags).
// ---------------------------------------------------------------------------
__global__ __launch_bounds__(384) void wt_kernel(
    const float* __restrict__ wq, const float* __restrict__ wk,
    const float* __restrict__ wv, float* __restrict__ wt,
    unsigned short* __restrict__ wvb, int do_wvb)
{
    const int c = blockIdx.x;          // 0..255
    const int r = threadIdx.x;         // 0..383
    float v;
    if      (r < 64)  v = wq[(size_t)r * C_ + c];
    else if (r < 128) v = wk[(size_t)(r - 64) * C_ + c];
    else              v = wv[(size_t)(r - 128) * C_ + c];
    wt[(size_t)c * 384 + r] = v;
    if (do_wvb && r >= 128) {
        const int e = c, cc = r - 128;
        wvb[(size_t)e * C_ + cc] = f2bf(wv[(size_t)e * C_ + cc]);
    }
}

// ---------------------------------------------------------------------------
// Kernel 1: x (b,c,n) -> xtb (b,n,c) bf16, 64x64 LDS tile transpose.
// lid = (b&7) + 8*(nt + 16*ct) + 512*(b>>3); grid 2048.
// ---------------------------------------------------------------------------
__global__ __launch_bounds__(256) void xt_kernel(
    const float* __restrict__ x, unsigned short* __restrict__ xtb)
{
    const int lid = blockIdx.x;
    const int b     = (lid & 7) + 8 * (lid >> 9);
    const int inner = (lid >> 3) & 63;
    const int nt    = inner & 15;
    const int ct    = inner >> 4;
    const int n0 = nt * 64, c0 = ct * 64;
    const int t  = threadIdx.x;

    __shared__ __align__(16) float tl[64][65];

    const float* xb = x + (size_t)b * C_ * N_;
    #pragma unroll
    for (int p = 0; p < 4; ++p) {
        const int cl = (t >> 4) + p * 16;
        const int nl = (t & 15) * 4;
        *(float4*)&tl[cl][nl] = *(const float4*)&xb[(size_t)(c0 + cl) * N_ + n0 + nl];
    }
    __syncthreads();

    unsigned short* dstb = xtb + ((size_t)b * N_) * C_;
    #pragma unroll
    for (int p = 0; p < 4; ++p) {
        const int nl = (t >> 4) + p * 16;
        const int cl = (t & 15) * 4;
        ushort4 o;
        o.x = f2bf(tl[cl + 0][nl]);
        o.y = f2bf(tl[cl + 1][nl]);
        o.z = f2bf(tl[cl + 2][nl]);
        o.w = f2bf(tl[cl + 3][nl]);
        *(ushort4*)&dstb[(size_t)(n0 + nl) * C_ + c0 + cl] = o;
    }
}

// ---------------------------------------------------------------------------
// Kernel 2a: q,k projection only (bit-exact ascending-c fmaf chain).
// lid = (b&7) + 8*(rg + 8*nt) + 256*(b>>3); grid 1024.
// ---------------------------------------------------------------------------
__global__ __launch_bounds__(256) void projqk_kernel(
    const float* __restrict__ x, const float* __restrict__ wt,
    const float* __restrict__ bq, const float* __restrict__ bk,
    float* __restrict__ qk)
{
    const int lid = blockIdx.x;
    const int b     = (lid & 7) + 8 * (lid >> 8);
    const int inner = (lid >> 3) & 31;
    const int rg    = inner & 7;
    const int nt    = inner >> 3;
    const int r0 = rg * 16;
    const int n0 = nt * 256;
    const int lane = threadIdx.x & 63;
    const int wu = __builtin_amdgcn_readfirstlane(threadIdx.x >> 6);
    const int rw = r0 + wu * 4;

    float acc[4][4];
    #pragma unroll
    for (int i = 0; i < 4; ++i)
        #pragma unroll
        for (int j = 0; j < 4; ++j) acc[i][j] = 0.f;

    const float* xp = x + (size_t)b * C_ * N_ + n0 + lane * 4;
    const float* wp = wt + rw;

    #pragma unroll 8
    for (int c = 0; c < C_; ++c) {
        const float4 xv = *(const float4*)(xp + (size_t)c * N_);
        const float4 w0 = *(const float4*)(wp + (size_t)c * 384);
        const float wv4[4] = { w0.x, w0.y, w0.z, w0.w };
        #pragma unroll
        for (int i = 0; i < 4; ++i) {
            acc[i][0] = fmaf(wv4[i], xv.x, acc[i][0]);
            acc[i][1] = fmaf(wv4[i], xv.y, acc[i][1]);
            acc[i][2] = fmaf(wv4[i], xv.z, acc[i][2]);
            acc[i][3] = fmaf(wv4[i], xv.w, acc[i][3]);
        }
    }

    #pragma unroll
    for (int i = 0; i < 4; ++i) {
        const int R = rw + i;
        const float bb = (R < 64) ? bq[R] : bk[R - 64];
        float4 o; o.x = acc[i][0]+bb; o.y = acc[i][1]+bb; o.z = acc[i][2]+bb; o.w = acc[i][3]+bb;
        *(float4*)&qk[((size_t)b * 128 + R) * N_ + n0 + lane * 4] = o;
    }
}

// ---------------------------------------------------------------------------
// Kernel 2b: V projection via bf16 MFMA (continuous path, 2% tolerance).
// lid = (b&7) + 8*(nb + 16*eb) + 512*(b>>3); grid 2048.
// ---------------------------------------------------------------------------
__global__ __launch_bounds__(256) void vmfma_kernel(
    const unsigned short* __restrict__ xtb, const unsigned short* __restrict__ wvb,
    const float* __restrict__ bv, float* __restrict__ vt)
{
    const int lid = blockIdx.x;
    const int b     = (lid & 7) + 8 * (lid >> 9);
    const int inner = (lid >> 3) & 63;
    const int nb    = inner & 15;
    const int eb    = inner >> 4;
    const int t  = threadIdx.x;
    const int lane = t & 63;
    const int w  = t >> 6;
    const int n_base = nb * 64 + (w & 1) * 32;
    const int e_base = eb * 64 + (w >> 1) * 32;

    const int l16  = lane & 15;
    const int koff = 8 * (lane >> 4);

    f32x4 acc[2][2];
    #pragma unroll
    for (int i = 0; i < 2; ++i)
        #pragma unroll
        for (int j = 0; j < 2; ++j) acc[i][j] = (f32x4)(0.f);

    const unsigned short* ab = wvb + (size_t)(e_base + l16) * C_ + koff;
    const unsigned short* bb = xtb + ((size_t)b * N_ + n_base + l16) * C_ + koff;

    #pragma unroll
    for (int kk = 0; kk < 8; ++kk) {
        const int c0 = kk * 32;
        bf16x8 a0 = *(const bf16x8*)(ab + c0);
        bf16x8 a1 = *(const bf16x8*)(ab + 16 * C_ + c0);
        bf16x8 b0 = *(const bf16x8*)(bb + c0);
        bf16x8 b1 = *(const bf16x8*)(bb + 16 * C_ + c0);
        acc[0][0] = __builtin_amdgcn_mfma_f32_16x16x32_bf16(a0, b0, acc[0][0], 0, 0, 0);
        acc[0][1] = __builtin_amdgcn_mfma_f32_16x16x32_bf16(a0, b1, acc[0][1], 0, 0, 0);
        acc[1][0] = __builtin_amdgcn_mfma_f32_16x16x32_bf16(a1, b0, acc[1][0], 0, 0, 0);
        acc[1][1] = __builtin_amdgcn_mfma_f32_16x16x32_bf16(a1, b1, acc[1][1], 0, 0, 0);
    }

    const int col  = lane & 15;
    const int row0 = (lane >> 4) * 4;
    #pragma unroll
    for (int i = 0; i < 2; ++i) {
        const int e0 = e_base + i * 16 + row0;
        const float4 bvv = *(const float4*)&bv[e0];
        #pragma unroll
        for (int j = 0; j < 2; ++j) {
            const int n = n_base + j * 16 + col;
            float4 o;
            o.x = acc[i][j][0] + bvv.x; o.y = acc[i][j][1] + bvv.y;
            o.z = acc[i][j][2] + bvv.z; o.w = acc[i][j][3] + bvv.w;
            *(float4*)&vt[((size_t)b * N_ + n) * C_ + e0] = o;
        }
    }
}

// ---------------------------------------------------------------------------
// Fallback: full projection (r16) if workspace too small for the MFMA path.
// ---------------------------------------------------------------------------
__global__ __launch_bounds__(256) void proj_full_kernel(
    const float* __restrict__ x, const float* __restrict__ wt,
    const float* __restrict__ bq, const float* __restrict__ bk,
    const float* __restrict__ bv,
    float* __restrict__ qk, float* __restrict__ vt)
{
    const int lid = blockIdx.x;
    const int b     = (lid & 7) + 8 * (lid / 384);
    const int inner = (lid >> 3) % 48;
    const int rg    = inner % 12;
    const int nt    = inner / 12;
    const int r0 = rg * 32;
    const int n0 = nt * 256;
    const int lane = threadIdx.x & 63;
    const int wu = __builtin_amdgcn_readfirstlane(threadIdx.x >> 6);
    const int rw = r0 + wu * 8;

    float acc[8][4];
    #pragma unroll
    for (int i = 0; i < 8; ++i)
        #pragma unroll
        for (int j = 0; j < 4; ++j) acc[i][j] = 0.f;

    const float* xp = x + (size_t)b * C_ * N_ + n0 + lane * 4;
    const float* wp = wt + rw;

    #pragma unroll 8
    for (int c = 0; c < C_; ++c) {
        const float4 xv = *(const float4*)(xp + (size_t)c * N_);
        const float* wr = wp + (size_t)c * 384;
        const float4 w0 = *(const float4*)(wr);
        const float4 w1 = *(const float4*)(wr + 4);
        const float wv8[8] = { w0.x, w0.y, w0.z, w0.w, w1.x, w1.y, w1.z, w1.w };
        #pragma unroll
        for (int i = 0; i < 8; ++i) {
            acc[i][0] = fmaf(wv8[i], xv.x, acc[i][0]);
            acc[i][1] = fmaf(wv8[i], xv.y, acc[i][1]);
            acc[i][2] = fmaf(wv8[i], xv.z, acc[i][2]);
            acc[i][3] = fmaf(wv8[i], xv.w, acc[i][3]);
        }
    }

    if (r0 < 128) {
        #pragma unroll
        for (int i = 0; i < 8; ++i) {
            const int R = rw + i;
            const float bb = (R < 64) ? bq[R] : bk[R - 64];
            float4 o; o.x = acc[i][0]+bb; o.y = acc[i][1]+bb; o.z = acc[i][2]+bb; o.w = acc[i][3]+bb;
            *(float4*)&qk[((size_t)b * 128 + R) * N_ + n0 + lane * 4] = o;
        }
    } else {
        const int e0 = rw - 128;
        float be[8];
        #pragma unroll
        for (int i = 0; i < 8; ++i) be[i] = bv[e0 + i];
        #pragma unroll
        for (int j = 0; j < 4; ++j) {
            const int n = n0 + lane * 4 + j;
            float* dst = &vt[((size_t)b * N_ + n) * C_ + e0];
            float4 o0; o0.x = acc[0][j]+be[0]; o0.y = acc[1][j]+be[1]; o0.z = acc[2][j]+be[2]; o0.w = acc[3][j]+be[3];
            float4 o1; o1.x = acc[4][j]+be[4]; o1.y = acc[5][j]+be[5]; o1.z = acc[6][j]+be[6]; o1.w = acc[7][j]+be[7];
            *(float4*)dst       = o0;
            *(float4*)(dst + 4) = o1;
        }
    }
}

// ---------------------------------------------------------------------------
// Kernel 3: attention. Sim (scalar fmaf, compiler-scheduled) + stage A (DPP
// threshold, cap-48 compaction + exact fallback) + stage B split-half DPP
// extraction + decode/softmax/batched gathers + residual write.
// ---------------------------------------------------------------------------
__global__ __launch_bounds__(512) void attn_kernel(
    const float* __restrict__ x,
    const float* __restrict__ qk,
    const float* __restrict__ vt,
    const float* __restrict__ scale,
    float* __restrict__ out)
{
    const int lid = blockIdx.x;
    const int b  = (lid & 7) + 8 * (lid >> 9);
    const int n0 = ((lid >> 3) & 63) * 16;
    const int t  = threadIdx.x;
    const int lane = t & 63;
    const int w  = t >> 6;
    const int ms = w & 3;
    const int rg = __builtin_amdgcn_readfirstlane(t >> 8);

    __shared__ unsigned long long cand[16][196];
    __shared__ int   ccnt[16][4];

    const int m_base = ms * 256 + lane * 4;

    float a0[8], a1[8], a2[8], a3[8];
    #pragma unroll
    for (int r = 0; r < 8; ++r) { a0[r]=0.f; a1[r]=0.f; a2[r]=0.f; a3[r]=0.f; }

    const float* kb = qk + ((size_t)b * 128 + 64) * N_ + m_base;
    const float* qb = qk + (size_t)b * 128 * N_ + n0 + rg * 8;

    #pragma unroll 2
    for (int d0 = 0; d0 < D_; d0 += 4) {
        const float4 k0 = *(const float4*)&kb[(size_t)(d0+0) * N_];
        const float4 k1 = *(const float4*)&kb[(size_t)(d0+1) * N_];
        const float4 k2 = *(const float4*)&kb[(size_t)(d0+2) * N_];
        const float4 k3 = *(const float4*)&kb[(size_t)(d0+3) * N_];

        float qs[4][8];
        #pragma unroll
        for (int dd = 0; dd < 4; ++dd) {
            #pragma unroll
            for (int rq = 0; rq < 2; ++rq) {
                const float4 qv = *(const float4*)&qb[(size_t)(d0 + dd) * N_ + rq * 4];
                qs[dd][rq*4+0] = qv.x; qs[dd][rq*4+1] = qv.y;
                qs[dd][rq*4+2] = qv.z; qs[dd][rq*4+3] = qv.w;
            }
        }

        #pragma unroll
        for (int r = 0; r < 8; ++r) {
            a0[r] = fmaf(qs[0][r], k0.x, a0[r]); a0[r] = fmaf(qs[1][r], k1.x, a0[r]);
            a0[r] = fmaf(qs[2][r], k2.x, a0[r]); a0[r] = fmaf(qs[3][r], k3.x, a0[r]);
            a1[r] = fmaf(qs[0][r], k0.y, a1[r]); a1[r] = fmaf(qs[1][r], k1.y, a1[r]);
            a1[r] = fmaf(qs[2][r], k2.y, a1[r]); a1[r] = fmaf(qs[3][r], k3.y, a1[r]);
            a2[r] = fmaf(qs[0][r], k0.z, a2[r]); a2[r] = fmaf(qs[1][r], k1.z, a2[r]);
            a2[r] = fmaf(qs[2][r], k2.z, a2[r]); a2[r] = fmaf(qs[3][r], k3.z, a2[r]);
            a3[r] = fmaf(qs[0][r], k0.w, a3[r]); a3[r] = fmaf(qs[1][r], k1.w, a3[r]);
            a3[r] = fmaf(qs[2][r], k2.w, a3[r]); a3[r] = fmaf(qs[3][r], k3.w, a3[r]);
        }
    }

    // ---- stage A: per-slice threshold filter + compaction (exact superset) ----
    const unsigned long long lt = (1ull << lane) - 1ull;
    #pragma unroll
    for (int r = 0; r < 8; ++r) {
        const int ri = rg * 8 + r;
        const int nrow = n0 + ri;
        float t0 = a0[r], t1 = a1[r], t2 = a2[r], t3 = a3[r];
        const int dj = nrow - m_base;
        if      (dj == 0) t0 = -1.0e9f;
        else if (dj == 1) t1 = -1.0e9f;
        else if (dj == 2) t2 = -1.0e9f;
        else if (dj == 3) t3 = -1.0e9f;

        float lm = fmaxf(fmaxf(t0, t1), fmaxf(t2, t3));
        lm = fmaxf(lm, dpp_mov_f<DPP_QUAD_XOR1>(lm));
        lm = fmaxf(lm, dpp_mov_f<DPP_QUAD_XOR2>(lm));
        lm = fmaxf(lm, dpp_mov_f<DPP_HALF_MIRROR>(lm));
        float Th = fminf(lm, dpp_mov_f<DPP_ROW_ROR8>(lm));
        Th = fminf(Th, __shfl_xor(Th, 16));
        Th = fminf(Th, __shfl_xor(Th, 32));

        int cnt = 0;
        {
            const bool p = (t0 >= Th);
            const unsigned long long msk = __ballot(p);
            const int pos = cnt + (int)__popcll(msk & lt);
            if (p && pos < 48) cand[ri][ms * 49 + pos] = pack_key(t0, m_base + 0);
            cnt += (int)__popcll(msk);
        }
        {
            const bool p = (t1 >= Th);
            const unsigned long long msk = __ballot(p);
            const int pos = cnt + (int)__popcll(msk & lt);
            if (p && pos < 48) cand[ri][ms * 49 + pos] = pack_key(t1, m_base + 1);
            cnt += (int)__popcll(msk);
        }
        {
            const bool p = (t2 >= Th);
            const unsigned long long msk = __ballot(p);
            const int pos = cnt + (int)__popcll(msk & lt);
            if (p && pos < 48) cand[ri][ms * 49 + pos] = pack_key(t2, m_base + 2);
            cnt += (int)__popcll(msk);
        }
        {
            const bool p = (t3 >= Th);
            const unsigned long long msk = __ballot(p);
            const int pos = cnt + (int)__popcll(msk & lt);
            if (p && pos < 48) cand[ri][ms * 49 + pos] = pack_key(t3, m_base + 3);
            cnt += (int)__popcll(msk);
        }

        if (cnt > 48) {   // exact fallback: slice top-8 via 8 extraction rounds
            unsigned long long K0 = pack_key(t0, m_base + 0);
            unsigned long long K1 = pack_key(t1, m_base + 1);
            unsigned long long K2 = pack_key(t2, m_base + 2);
            unsigned long long K3 = pack_key(t3, m_base + 3);
            #pragma unroll 1
            for (int round = 0; round < 8; ++round) {
                unsigned long long kl = K0 > K1 ? K0 : K1;
                kl = K2 > kl ? K2 : kl;
                kl = K3 > kl ? K3 : kl;
                #pragma unroll
                for (int off = 32; off >= 1; off >>= 1) {
                    const unsigned long long ks = __shfl_xor(kl, off);
                    if (ks > kl) kl = ks;
                }
                if (lane == 0) cand[ri][ms * 49 + round] = kl;
                if      (K0 == kl) K0 = 0ull;
                else if (K1 == kl) K1 = 0ull;
                else if (K2 == kl) K2 = 0ull;
                else if (K3 == kl) K3 = 0ull;
            }
            cnt = 8;
        }
        if (lane == 0) ccnt[ri][ms] = cnt;
    }
    __syncthreads();

    // ---- stage B: split-half extraction (2 rows concurrently per wave) ----
    {
        const int half = lane >> 5;          // 0 -> row w*2, 1 -> row w*2+1
        const int r    = w * 2 + half;
        const int l5   = lane & 31;

        unsigned long long k[6];
        #pragma unroll
        for (int s = 0; s < 4; ++s)
            k[s] = (l5 < ccnt[r][s]) ? cand[r][s * 49 + l5] : 0ull;
        #pragma unroll
        for (int j = 0; j < 2; ++j) {
            const int g   = l5 + 32 * j;     // 0..63
            const int s   = g >> 4;          // 0..3
            const int pos = 32 + (g & 15);   // 32..47
            k[4 + j] = (pos < ccnt[r][s]) ? cand[r][s * 49 + pos] : 0ull;
        }

        #pragma unroll 1
        for (int round = 0; round < 8; ++round) {
            unsigned long long km = k[0];
            #pragma unroll
            for (int q = 1; q < 6; ++q) km = k[q] > km ? k[q] : km;
            km = dpp_max_u64<DPP_QUAD_XOR1>(km);
            km = dpp_max_u64<DPP_QUAD_XOR2>(km);
            km = dpp_max_u64<DPP_HALF_MIRROR>(km);
            km = dpp_max_u64<DPP_ROW_ROR8>(km);
            { const unsigned long long p = __shfl_xor(km, 16); km = p > km ? p : km; }
            if (l5 == 0) cand[r][188 + round] = km;   // winners, clear of union
            #pragma unroll
            for (int q = 0; q < 6; ++q) if (k[q] == km) k[q] = 0ull;
        }
    }

    // ---- decode winners + softmax + batched V gathers (all 64 lanes/row) ----
    const float* vtb = vt + (size_t)b * N_ * C_;
    #pragma unroll 1
    for (int rr = 0; rr < 2; ++rr) {
        const int r = w * 2 + rr;
        float ev[8]; unsigned int mi[8];
        float S = 0.f, vmax = 0.f;
        #pragma unroll
        for (int j = 0; j < 8; ++j) {
            const unsigned long long km = cand[r][188 + j];
            const unsigned int mono = (unsigned int)(km >> 10);
            mi[j] = 1023u - ((unsigned int)km & 1023u);
            const unsigned int bits = (mono & 0x80000000u) ? (mono & 0x7FFFFFFFu) : ~mono;
            const float vraw = __uint_as_float(bits);
            if (j == 0) vmax = vraw;
            const float e = __expf((vraw - vmax) * 0.125f);
            S += e;
            ev[j] = e;
        }

        float4 o = make_float4(0.f, 0.f, 0.f, 0.f);
        #pragma unroll
        for (int j = 0; j < 8; ++j) {
            const float4 vv = *(const float4*)&vtb[(size_t)mi[j] * C_ + lane * 4];
            o.x += ev[j] * vv.x; o.y += ev[j] * vv.y;
            o.z += ev[j] * vv.z; o.w += ev[j] * vv.w;
        }
        const float inv = 1.f / S;
        float* orow = (float*)&cand[r][0];   // union: out row over cand row r
        *(float4*)&orow[lane * 4] = make_float4(o.x*inv, o.y*inv, o.z*inv, o.w*inv);
    }
    __syncthreads();

    // ---- residual + (b, c, n) write ----
    const float sc = scale[0];
    const float* xb = x + (size_t)b * C_ * N_;
    float* ob = out + (size_t)b * C_ * N_;
    const int nl = t & 15;
    const int cg = t >> 4;
    const float* orow = (const float*)&cand[nl][0];
    #pragma unroll
    for (int i = 0; i < 8; ++i) {
        const int cc = i * 32 + cg;
        const size_t gi = (size_t)cc * N_ + n0 + nl;
        ob[gi] = xb[gi] + sc * orow[cc];
    }
}

extern "C" void kernel_launch(void* const* d_in, const int* in_sizes, int n_in,
                              void* d_out, int out_size, void* d_ws, size_t ws_size,
                              hipStream_t stream) {
    const float* x     = (const float*)d_in[0];
    const float* wq    = (const float*)d_in[1];
    const float* bq    = (const float*)d_in[2];
    const float* wk    = (const float*)d_in[3];
    const float* bk    = (const float*)d_in[4];
    const float* wv    = (const float*)d_in[5];
    const float* bv    = (const float*)d_in[6];
    const float* scale = (const float*)d_in[7];
    float* out = (float*)d_out;

    float* qk = (float*)d_ws;                         // 16.78 MB
    float* vt = qk + (size_t)B_ * 128 * N_;           // 33.55 MB
    float* wt = vt + (size_t)B_ * N_ * C_;            //  0.39 MB
    unsigned short* wvb = (unsigned short*)(wt + 256 * 384);   // 0.13 MB
    unsigned short* xtb = wvb + (size_t)C_ * C_;               // 16.78 MB

    const size_t needed = ((char*)(xtb + (size_t)B_ * N_ * C_)) - (char*)d_ws;
    const int mfma_path = (ws_size >= needed) ? 1 : 0;

    wt_kernel<<<dim3(256), 384, 0, stream>>>(wq, wk, wv, wt, wvb, mfma_path);
    if (mfma_path) {
        xt_kernel<<<dim3(2048), 256, 0, stream>>>(x, xtb);
        projqk_kernel<<<dim3(1024), 256, 0, stream>>>(x, wt, bq, bk, qk);
        vmfma_kernel<<<dim3(2048), 256, 0, stream>>>(xtb, wvb, bv, vt);
    } else {
        proj_full_kernel<<<dim3(1536), 256, 0, stream>>>(x, wt, bq, bk, bv, qk, vt);
    }
    attn_kernel<<<dim3(2048), 512, 0, stream>>>(x, qk, vt, scale, out);
}

// Round 21
// 172.548 us; speedup vs baseline: 1.3741x; 1.0312x over previous
//
#include <hip/hip_runtime.h>
#include <hip/hip_bf16.h>

#define B_ 32
#define C_ 256
#define N_ 1024
#define D_ 64

typedef __attribute__((ext_vector_type(8))) short bf16x8;
typedef __attribute__((ext_vector_type(4))) float f32x4;

// key = (monotone(v) << 10) | (1023 - m): larger key <=> larger v, tie -> smaller m.
__device__ __forceinline__ unsigned long long pack_key(float v, int m) {
    const unsigned int bits = __float_as_uint(v);
    const unsigned int mono = (bits & 0x80000000u) ? ~bits : (bits | 0x80000000u);
    return ((unsigned long long)mono << 10) | (unsigned long long)(1023 - m);
}

// DPP cross-lane move (VALU pipe, not DS). ctrl must be an immediate -> template.
template <int CTRL>
__device__ __forceinline__ float dpp_mov_f(float x) {
    return __int_as_float(__builtin_amdgcn_update_dpp(
        0, __float_as_int(x), CTRL, 0xF, 0xF, true));
}
#define DPP_QUAD_XOR1   0xB1
#define DPP_QUAD_XOR2   0x4E
#define DPP_HALF_MIRROR 0x141
#define DPP_ROW_ROR8    0x128

// u64 max with DPP-permuted partner (xor1/2/4/8 patterns; VALU only).
template <int CTRL>
__device__ __forceinline__ unsigned long long dpp_max_u64(unsigned long long k) {
    const unsigned int lo = (unsigned int)k;
    const unsigned int hi = (unsigned int)(k >> 32);
    const unsigned int plo = (unsigned int)__builtin_amdgcn_update_dpp(0, (int)lo, CTRL, 0xF, 0xF, true);
    const unsigned int phi = (unsigned int)__builtin_amdgcn_update_dpp(0, (int)hi, CTRL, 0xF, 0xF, true);
    const unsigned long long p = ((unsigned long long)phi << 32) | plo;
    return p > k ? p : k;
}

__device__ __forceinline__ unsigned short f2bf(float f) {
    __hip_bfloat16 h = __float2bfloat16(f);
    return *(unsigned short*)&h;
}

// ---------------------------------------------------------------------------
// Fused kernel A: blocks 0..255 = wt (+wvb bf16 copy); blocks 256..2303 = xt
// (x (b,c,n) -> xtb (b,n,c) bf16 via 64x64 LDS tile transpose).
// xt lid = (b&7) + 8*(nt + 16*ct) + 512*(b>>3).
// ---------------------------------------------------------------------------
__global__ __launch_bounds__(256) void prep_kernel(
    const float* __restrict__ x,
    const float* __restrict__ wq, const float* __restrict__ wk,
    const float* __restrict__ wv, float* __restrict__ wt,
    unsigned short* __restrict__ wvb, unsigned short* __restrict__ xtb,
    int mfma_path)
{
    __shared__ __align__(16) float tl[64][65];
    const int bid = blockIdx.x;
    const int t = threadIdx.x;

    if (bid < 256) {
        const int c = bid;
        for (int r = t; r < 384; r += 256) {
            float v;
            if      (r < 64)  v = wq[(size_t)r * C_ + c];
            else if (r < 128) v = wk[(size_t)(r - 64) * C_ + c];
            else              v = wv[(size_t)(r - 128) * C_ + c];
            wt[(size_t)c * 384 + r] = v;
        }
        if (mfma_path) wvb[(size_t)c * C_ + t] = f2bf(wv[(size_t)c * C_ + t]);
        return;
    }
    if (!mfma_path) return;

    const int lid = bid - 256;
    const int b     = (lid & 7) + 8 * (lid >> 9);
    const int inner = (lid >> 3) & 63;
    const int nt    = inner & 15;
    const int ct    = inner >> 4;
    const int n0 = nt * 64, c0 = ct * 64;

    const float* xb = x + (size_t)b * C_ * N_;
    #pragma unroll
    for (int p = 0; p < 4; ++p) {
        const int cl = (t >> 4) + p * 16;
        const int nl = (t & 15) * 4;
        *(float4*)&tl[cl][nl] = *(const float4*)&xb[(size_t)(c0 + cl) * N_ + n0 + nl];
    }
    __syncthreads();

    unsigned short* dstb = xtb + ((size_t)b * N_) * C_;
    #pragma unroll
    for (int p = 0; p < 4; ++p) {
        const int nl = (t >> 4) + p * 16;
        const int cl = (t & 15) * 4;
        ushort4 o;
        o.x = f2bf(tl[cl + 0][nl]);
        o.y = f2bf(tl[cl + 1][nl]);
        o.z = f2bf(tl[cl + 2][nl]);
        o.w = f2bf(tl[cl + 3][nl]);
        *(ushort4*)&dstb[(size_t)(n0 + nl) * C_ + c0 + cl] = o;
    }
}

// ---------------------------------------------------------------------------
// Fused kernel B: blocks 0..1023 = q,k projection (r18 scalar fmaf body,
// bit-exact ascending-c chain); blocks 1024..3071 = V projection via bf16
// MFMA (r18 body). Per-block uniform branch; co-residency hides both tails.
// ---------------------------------------------------------------------------
__global__ __launch_bounds__(256) void projfused_kernel(
    const float* __restrict__ x, const float* __restrict__ wt,
    const float* __restrict__ bq, const float* __restrict__ bk,
    float* __restrict__ qk,
    const unsigned short* __restrict__ xtb, const unsigned short* __restrict__ wvb,
    const float* __restrict__ bv, float* __restrict__ vt)
{
    const int bid = blockIdx.x;
    const int t = threadIdx.x;
    const int lane = t & 63;

    if (bid < 1024) {
        // ---- q,k: bit-exact ascending-c fmaf chain (r18 body verbatim) ----
        const int lid = bid;
        const int b     = (lid & 7) + 8 * (lid >> 8);
        const int inner = (lid >> 3) & 31;
        const int rg    = inner & 7;
        const int nt    = inner >> 3;
        const int r0 = rg * 16;
        const int n0 = nt * 256;
        const int wu = __builtin_amdgcn_readfirstlane(t >> 6);
        const int rw = r0 + wu * 4;

        float acc[4][4];
        #pragma unroll
        for (int i = 0; i < 4; ++i)
            #pragma unroll
            for (int j = 0; j < 4; ++j) acc[i][j] = 0.f;

        const float* xp = x + (size_t)b * C_ * N_ + n0 + lane * 4;
        const float* wp = wt + rw;

        #pragma unroll 8
        for (int c = 0; c < C_; ++c) {
            const float4 xv = *(const float4*)(xp + (size_t)c * N_);
            const float4 w0 = *(const float4*)(wp + (size_t)c * 384);   // uniform s_load
            const float wv4[4] = { w0.x, w0.y, w0.z, w0.w };
            #pragma unroll
            for (int i = 0; i < 4; ++i) {
                acc[i][0] = fmaf(wv4[i], xv.x, acc[i][0]);
                acc[i][1] = fmaf(wv4[i], xv.y, acc[i][1]);
                acc[i][2] = fmaf(wv4[i], xv.z, acc[i][2]);
                acc[i][3] = fmaf(wv4[i], xv.w, acc[i][3]);
            }
        }

        #pragma unroll
        for (int i = 0; i < 4; ++i) {
            const int R = rw + i;
            const float bb = (R < 64) ? bq[R] : bk[R - 64];
            float4 o; o.x = acc[i][0]+bb; o.y = acc[i][1]+bb; o.z = acc[i][2]+bb; o.w = acc[i][3]+bb;
            *(float4*)&qk[((size_t)b * 128 + R) * N_ + n0 + lane * 4] = o;
        }
    } else {
        // ---- V via bf16 MFMA (continuous path, 2% tolerance; r18 body) ----
        const int lid = bid - 1024;
        const int b     = (lid & 7) + 8 * (lid >> 9);
        const int inner = (lid >> 3) & 63;
        const int nb    = inner & 15;
        const int eb    = inner >> 4;
        const int w  = t >> 6;
        const int n_base = nb * 64 + (w & 1) * 32;
        const int e_base = eb * 64 + (w >> 1) * 32;

        const int l16  = lane & 15;
        const int koff = 8 * (lane >> 4);

        f32x4 acc[2][2];
        #pragma unroll
        for (int i = 0; i < 2; ++i)
            #pragma unroll
            for (int j = 0; j < 2; ++j) acc[i][j] = (f32x4)(0.f);

        const unsigned short* ab = wvb + (size_t)(e_base + l16) * C_ + koff;
        const unsigned short* bb = xtb + ((size_t)b * N_ + n_base + l16) * C_ + koff;

        #pragma unroll
        for (int kk = 0; kk < 8; ++kk) {
            const int c0 = kk * 32;
            bf16x8 a0 = *(const bf16x8*)(ab + c0);
            bf16x8 a1 = *(const bf16x8*)(ab + 16 * C_ + c0);
            bf16x8 b0 = *(const bf16x8*)(bb + c0);
            bf16x8 b1 = *(const bf16x8*)(bb + 16 * C_ + c0);
            acc[0][0] = __builtin_amdgcn_mfma_f32_16x16x32_bf16(a0, b0, acc[0][0], 0, 0, 0);
            acc[0][1] = __builtin_amdgcn_mfma_f32_16x16x32_bf16(a0, b1, acc[0][1], 0, 0, 0);
            acc[1][0] = __builtin_amdgcn_mfma_f32_16x16x32_bf16(a1, b0, acc[1][0], 0, 0, 0);
            acc[1][1] = __builtin_amdgcn_mfma_f32_16x16x32_bf16(a1, b1, acc[1][1], 0, 0, 0);
        }

        const int col  = lane & 15;
        const int row0 = (lane >> 4) * 4;
        #pragma unroll
        for (int i = 0; i < 2; ++i) {
            const int e0 = e_base + i * 16 + row0;
            const float4 bvv = *(const float4*)&bv[e0];
            #pragma unroll
            for (int j = 0; j < 2; ++j) {
                const int n = n_base + j * 16 + col;
                float4 o;
                o.x = acc[i][j][0] + bvv.x; o.y = acc[i][j][1] + bvv.y;
                o.z = acc[i][j][2] + bvv.z; o.w = acc[i][j][3] + bvv.w;
                *(float4*)&vt[((size_t)b * N_ + n) * C_ + e0] = o;
            }
        }
    }
}

// ---------------------------------------------------------------------------
// Fallback: full projection (r16) if workspace too small for the MFMA path.
// ---------------------------------------------------------------------------
__global__ __launch_bounds__(256) void proj_full_kernel(
    const float* __restrict__ x, const float* __restrict__ wt,
    const float* __restrict__ bq, const float* __restrict__ bk,
    const float* __restrict__ bv,
    float* __restrict__ qk, float* __restrict__ vt)
{
    const int lid = blockIdx.x;
    const int b     = (lid & 7) + 8 * (lid / 384);
    const int inner = (lid >> 3) % 48;
    const int rg    = inner % 12;
    const int nt    = inner / 12;
    const int r0 = rg * 32;
    const int n0 = nt * 256;
    const int lane = threadIdx.x & 63;
    const int wu = __builtin_amdgcn_readfirstlane(threadIdx.x >> 6);
    const int rw = r0 + wu * 8;

    float acc[8][4];
    #pragma unroll
    for (int i = 0; i < 8; ++i)
        #pragma unroll
        for (int j = 0; j < 4; ++j) acc[i][j] = 0.f;

    const float* xp = x + (size_t)b * C_ * N_ + n0 + lane * 4;
    const float* wp = wt + rw;

    #pragma unroll 8
    for (int c = 0; c < C_; ++c) {
        const float4 xv = *(const float4*)(xp + (size_t)c * N_);
        const float* wr = wp + (size_t)c * 384;
        const float4 w0 = *(const float4*)(wr);
        const float4 w1 = *(const float4*)(wr + 4);
        const float wv8[8] = { w0.x, w0.y, w0.z, w0.w, w1.x, w1.y, w1.z, w1.w };
        #pragma unroll
        for (int i = 0; i < 8; ++i) {
            acc[i][0] = fmaf(wv8[i], xv.x, acc[i][0]);
            acc[i][1] = fmaf(wv8[i], xv.y, acc[i][1]);
            acc[i][2] = fmaf(wv8[i], xv.z, acc[i][2]);
            acc[i][3] = fmaf(wv8[i], xv.w, acc[i][3]);
        }
    }

    if (r0 < 128) {
        #pragma unroll
        for (int i = 0; i < 8; ++i) {
            const int R = rw + i;
            const float bb = (R < 64) ? bq[R] : bk[R - 64];
            float4 o; o.x = acc[i][0]+bb; o.y = acc[i][1]+bb; o.z = acc[i][2]+bb; o.w = acc[i][3]+bb;
            *(float4*)&qk[((size_t)b * 128 + R) * N_ + n0 + lane * 4] = o;
        }
    } else {
        const int e0 = rw - 128;
        float be[8];
        #pragma unroll
        for (int i = 0; i < 8; ++i) be[i] = bv[e0 + i];
        #pragma unroll
        for (int j = 0; j < 4; ++j) {
            const int n = n0 + lane * 4 + j;
            float* dst = &vt[((size_t)b * N_ + n) * C_ + e0];
            float4 o0; o0.x = acc[0][j]+be[0]; o0.y = acc[1][j]+be[1]; o0.z = acc[2][j]+be[2]; o0.w = acc[3][j]+be[3];
            float4 o1; o1.x = acc[4][j]+be[4]; o1.y = acc[5][j]+be[5]; o1.z = acc[6][j]+be[6]; o1.w = acc[7][j]+be[7];
            *(float4*)dst       = o0;
            *(float4*)(dst + 4) = o1;
        }
    }
}

// ---------------------------------------------------------------------------
// Kernel 3: attention (r18/r20 verbatim). Sim (scalar fmaf) + stage A (DPP
// threshold, cap-48 compaction + exact fallback) + stage B split-half DPP
// extraction + decode/softmax/batched gathers + residual write.
// ---------------------------------------------------------------------------
__global__ __launch_bounds__(512) void attn_kernel(
    const float* __restrict__ x,
    const float* __restrict__ qk,
    const float* __restrict__ vt,
    const float* __restrict__ scale,
    float* __restrict__ out)
{
    const int lid = blockIdx.x;
    const int b  = (lid & 7) + 8 * (lid >> 9);
    const int n0 = ((lid >> 3) & 63) * 16;
    const int t  = threadIdx.x;
    const int lane = t & 63;
    const int w  = t >> 6;
    const int ms = w & 3;
    const int rg = __builtin_amdgcn_readfirstlane(t >> 8);

    __shared__ unsigned long long cand[16][196];
    __shared__ int   ccnt[16][4];

    const int m_base = ms * 256 + lane * 4;

    float a0[8], a1[8], a2[8], a3[8];
    #pragma unroll
    for (int r = 0; r < 8; ++r) { a0[r]=0.f; a1[r]=0.f; a2[r]=0.f; a3[r]=0.f; }

    const float* kb = qk + ((size_t)b * 128 + 64) * N_ + m_base;
    const float* qb = qk + (size_t)b * 128 * N_ + n0 + rg * 8;

    #pragma unroll 2
    for (int d0 = 0; d0 < D_; d0 += 4) {
        const float4 k0 = *(const float4*)&kb[(size_t)(d0+0) * N_];
        const float4 k1 = *(const float4*)&kb[(size_t)(d0+1) * N_];
        const float4 k2 = *(const float4*)&kb[(size_t)(d0+2) * N_];
        const float4 k3 = *(const float4*)&kb[(size_t)(d0+3) * N_];

        float qs[4][8];
        #pragma unroll
        for (int dd = 0; dd < 4; ++dd) {
            #pragma unroll
            for (int rq = 0; rq < 2; ++rq) {
                const float4 qv = *(const float4*)&qb[(size_t)(d0 + dd) * N_ + rq * 4];
                qs[dd][rq*4+0] = qv.x; qs[dd][rq*4+1] = qv.y;
                qs[dd][rq*4+2] = qv.z; qs[dd][rq*4+3] = qv.w;
            }
        }

        #pragma unroll
        for (int r = 0; r < 8; ++r) {
            a0[r] = fmaf(qs[0][r], k0.x, a0[r]); a0[r] = fmaf(qs[1][r], k1.x, a0[r]);
            a0[r] = fmaf(qs[2][r], k2.x, a0[r]); a0[r] = fmaf(qs[3][r], k3.x, a0[r]);
            a1[r] = fmaf(qs[0][r], k0.y, a1[r]); a1[r] = fmaf(qs[1][r], k1.y, a1[r]);
            a1[r] = fmaf(qs[2][r], k2.y, a1[r]); a1[r] = fmaf(qs[3][r], k3.y, a1[r]);
            a2[r] = fmaf(qs[0][r], k0.z, a2[r]); a2[r] = fmaf(qs[1][r], k1.z, a2[r]);
            a2[r] = fmaf(qs[2][r], k2.z, a2[r]); a2[r] = fmaf(qs[3][r], k3.z, a2[r]);
            a3[r] = fmaf(qs[0][r], k0.w, a3[r]); a3[r] = fmaf(qs[1][r], k1.w, a3[r]);
            a3[r] = fmaf(qs[2][r], k2.w, a3[r]); a3[r] = fmaf(qs[3][r], k3.w, a3[r]);
        }
    }

    // ---- stage A: per-slice threshold filter + compaction (exact superset) ----
    const unsigned long long lt = (1ull << lane) - 1ull;
    #pragma unroll
    for (int r = 0; r < 8; ++r) {
        const int ri = rg * 8 + r;
        const int nrow = n0 + ri;
        float t0 = a0[r], t1 = a1[r], t2 = a2[r], t3 = a3[r];
        const int dj = nrow - m_base;
        if      (dj == 0) t0 = -1.0e9f;
        else if (dj == 1) t1 = -1.0e9f;
        else if (dj == 2) t2 = -1.0e9f;
        else if (dj == 3) t3 = -1.0e9f;

        float lm = fmaxf(fmaxf(t0, t1), fmaxf(t2, t3));
        lm = fmaxf(lm, dpp_mov_f<DPP_QUAD_XOR1>(lm));
        lm = fmaxf(lm, dpp_mov_f<DPP_QUAD_XOR2>(lm));
        lm = fmaxf(lm, dpp_mov_f<DPP_HALF_MIRROR>(lm));
        float Th = fminf(lm, dpp_mov_f<DPP_ROW_ROR8>(lm));
        Th = fminf(Th, __shfl_xor(Th, 16));
        Th = fminf(Th, __shfl_xor(Th, 32));

        int cnt = 0;
        {
            const bool p = (t0 >= Th);
            const unsigned long long msk = __ballot(p);
            const int pos = cnt + (int)__popcll(msk & lt);
            if (p && pos < 48) cand[ri][ms * 49 + pos] = pack_key(t0, m_base + 0);
            cnt += (int)__popcll(msk);
        }
        {
            const bool p = (t1 >= Th);
            const unsigned long long msk = __ballot(p);
            const int pos = cnt + (int)__popcll(msk & lt);
            if (p && pos < 48) cand[ri][ms * 49 + pos] = pack_key(t1, m_base + 1);
            cnt += (int)__popcll(msk);
        }
        {
            const bool p = (t2 >= Th);
            const unsigned long long msk = __ballot(p);
            const int pos = cnt + (int)__popcll(msk & lt);
            if (p && pos < 48) cand[ri][ms * 49 + pos] = pack_key(t2, m_base + 2);
            cnt += (int)__popcll(msk);
        }
        {
            const bool p = (t3 >= Th);
            const unsigned long long msk = __ballot(p);
            const int pos = cnt + (int)__popcll(msk & lt);
            if (p && pos < 48) cand[ri][ms * 49 + pos] = pack_key(t3, m_base + 3);
            cnt += (int)__popcll(msk);
        }

        if (cnt > 48) {   // exact fallback: slice top-8 via 8 extraction rounds
            unsigned long long K0 = pack_key(t0, m_base + 0);
            unsigned long long K1 = pack_key(t1, m_base + 1);
            unsigned long long K2 = pack_key(t2, m_base + 2);
            unsigned long long K3 = pack_key(t3, m_base + 3);
            #pragma unroll 1
            for (int round = 0; round < 8; ++round) {
                unsigned long long kl = K0 > K1 ? K0 : K1;
                kl = K2 > kl ? K2 : kl;
                kl = K3 > kl ? K3 : kl;
                #pragma unroll
                for (int off = 32; off >= 1; off >>= 1) {
                    const unsigned long long ks = __shfl_xor(kl, off);
                    if (ks > kl) kl = ks;
                }
                if (lane == 0) cand[ri][ms * 49 + round] = kl;
                if      (K0 == kl) K0 = 0ull;
                else if (K1 == kl) K1 = 0ull;
                else if (K2 == kl) K2 = 0ull;
                else if (K3 == kl) K3 = 0ull;
            }
            cnt = 8;
        }
        if (lane == 0) ccnt[ri][ms] = cnt;
    }
    __syncthreads();

    // ---- stage B: split-half extraction (2 rows concurrently per wave) ----
    {
        const int half = lane >> 5;          // 0 -> row w*2, 1 -> row w*2+1
        const int r    = w * 2 + half;
        const int l5   = lane & 31;

        unsigned long long k[6];
        #pragma unroll
        for (int s = 0; s < 4; ++s)
            k[s] = (l5 < ccnt[r][s]) ? cand[r][s * 49 + l5] : 0ull;
        #pragma unroll
        for (int j = 0; j < 2; ++j) {
            const int g   = l5 + 32 * j;     // 0..63
            const int s   = g >> 4;          // 0..3
            const int pos = 32 + (g & 15);   // 32..47
            k[4 + j] = (pos < ccnt[r][s]) ? cand[r][s * 49 + pos] : 0ull;
        }

        #pragma unroll 1
        for (int round = 0; round < 8; ++round) {
            unsigned long long km = k[0];
            #pragma unroll
            for (int q = 1; q < 6; ++q) km = k[q] > km ? k[q] : km;
            km = dpp_max_u64<DPP_QUAD_XOR1>(km);
            km = dpp_max_u64<DPP_QUAD_XOR2>(km);
            km = dpp_max_u64<DPP_HALF_MIRROR>(km);
            km = dpp_max_u64<DPP_ROW_ROR8>(km);
            { const unsigned long long p = __shfl_xor(km, 16); km = p > km ? p : km; }
            if (l5 == 0) cand[r][188 + round] = km;   // winners, clear of union
            #pragma unroll
            for (int q = 0; q < 6; ++q) if (k[q] == km) k[q] = 0ull;
        }
    }

    // ---- decode winners + softmax + batched V gathers (all 64 lanes/row) ----
    const float* vtb = vt + (size_t)b * N_ * C_;
    #pragma unroll 1
    for (int rr = 0; rr < 2; ++rr) {
        const int r = w * 2 + rr;
        float ev[8]; unsigned int mi[8];
        float S = 0.f, vmax = 0.f;
        #pragma unroll
        for (int j = 0; j < 8; ++j) {
            const unsigned long long km = cand[r][188 + j];
            const unsigned int mono = (unsigned int)(km >> 10);
            mi[j] = 1023u - ((unsigned int)km & 1023u);
            const unsigned int bits = (mono & 0x80000000u) ? (mono & 0x7FFFFFFFu) : ~mono;
            const float vraw = __uint_as_float(bits);
            if (j == 0) vmax = vraw;
            const float e = __expf((vraw - vmax) * 0.125f);
            S += e;
            ev[j] = e;
        }

        float4 o = make_float4(0.f, 0.f, 0.f, 0.f);
        #pragma unroll
        for (int j = 0; j < 8; ++j) {
            const float4 vv = *(const float4*)&vtb[(size_t)mi[j] * C_ + lane * 4];
            o.x += ev[j] * vv.x; o.y += ev[j] * vv.y;
            o.z += ev[j] * vv.z; o.w += ev[j] * vv.w;
        }
        const float inv = 1.f / S;
        float* orow = (float*)&cand[r][0];   // union: out row over cand row r
        *(float4*)&orow[lane * 4] = make_float4(o.x*inv, o.y*inv, o.z*inv, o.w*inv);
    }
    __syncthreads();

    // ---- residual + (b, c, n) write ----
    const float sc = scale[0];
    const float* xb = x + (size_t)b * C_ * N_;
    float* ob = out + (size_t)b * C_ * N_;
    const int nl = t & 15;
    const int cg = t >> 4;
    const float* orow = (const float*)&cand[nl][0];
    #pragma unroll
    for (int i = 0; i < 8; ++i) {
        const int cc = i * 32 + cg;
        const size_t gi = (size_t)cc * N_ + n0 + nl;
        ob[gi] = xb[gi] + sc * orow[cc];
    }
}

extern "C" void kernel_launch(void* const* d_in, const int* in_sizes, int n_in,
                              void* d_out, int out_size, void* d_ws, size_t ws_size,
                              hipStream_t stream) {
    const float* x     = (const float*)d_in[0];
    const float* wq    = (const float*)d_in[1];
    const float* bq    = (const float*)d_in[2];
    const float* wk    = (const float*)d_in[3];
    const float* bk    = (const float*)d_in[4];
    const float* wv    = (const float*)d_in[5];
    const float* bv    = (const float*)d_in[6];
    const float* scale = (const float*)d_in[7];
    float* out = (float*)d_out;

    float* qk = (float*)d_ws;                         // 16.78 MB
    float* vt = qk + (size_t)B_ * 128 * N_;           // 33.55 MB
    float* wt = vt + (size_t)B_ * N_ * C_;            //  0.39 MB
    unsigned short* wvb = (unsigned short*)(wt + 256 * 384);   // 0.13 MB
    unsigned short* xtb = wvb + (size_t)C_ * C_;               // 16.78 MB

    const size_t needed = ((char*)(xtb + (size_t)B_ * N_ * C_)) - (char*)d_ws;
    const int mfma_path = (ws_size >= needed) ? 1 : 0;

    prep_kernel<<<dim3(256 + 2048), 256, 0, stream>>>(x, wq, wk, wv, wt, wvb, xtb, mfma_path);
    if (mfma_path) {
        projfused_kernel<<<dim3(1024 + 2048), 256, 0, stream>>>(x, wt, bq, bk, qk, xtb, wvb, bv, vt);
    } else {
        proj_full_kernel<<<dim3(1536), 256, 0, stream>>>(x, wt, bq, bk, bv, qk, vt);
    }
    attn_kernel<<<dim3(2048), 512, 0, stream>>>(x, qk, vt, scale, out);
}

// Round 22
// 169.171 us; speedup vs baseline: 1.4015x; 1.0200x over previous
//
#include <hip/hip_runtime.h>
#include <hip/hip_bf16.h>

#define B_ 32
#define C_ 256
#define N_ 1024
#define D_ 64

typedef __attribute__((ext_vector_type(8))) short bf16x8;
typedef __attribute__((ext_vector_type(4))) float f32x4;

// key = (monotone(v) << 10) | (1023 - m): larger key <=> larger v, tie -> smaller m.
__device__ __forceinline__ unsigned long long pack_key(float v, int m) {
    const unsigned int bits = __float_as_uint(v);
    const unsigned int mono = (bits & 0x80000000u) ? ~bits : (bits | 0x80000000u);
    return ((unsigned long long)mono << 10) | (unsigned long long)(1023 - m);
}

// DPP cross-lane move (VALU pipe, not DS). ctrl must be an immediate -> template.
template <int CTRL>
__device__ __forceinline__ float dpp_mov_f(float x) {
    return __int_as_float(__builtin_amdgcn_update_dpp(
        0, __float_as_int(x), CTRL, 0xF, 0xF, true));
}
#define DPP_QUAD_XOR1   0xB1
#define DPP_QUAD_XOR2   0x4E
#define DPP_HALF_MIRROR 0x141
#define DPP_ROW_ROR8    0x128

// u64 max with DPP-permuted partner (xor1/2/4/8 patterns; VALU only).
template <int CTRL>
__device__ __forceinline__ unsigned long long dpp_max_u64(unsigned long long k) {
    const unsigned int lo = (unsigned int)k;
    const unsigned int hi = (unsigned int)(k >> 32);
    const unsigned int plo = (unsigned int)__builtin_amdgcn_update_dpp(0, (int)lo, CTRL, 0xF, 0xF, true);
    const unsigned int phi = (unsigned int)__builtin_amdgcn_update_dpp(0, (int)hi, CTRL, 0xF, 0xF, true);
    const unsigned long long p = ((unsigned long long)phi << 32) | plo;
    return p > k ? p : k;
}

__device__ __forceinline__ unsigned short f2bf(float f) {
    __hip_bfloat16 h = __float2bfloat16(f);
    return *(unsigned short*)&h;
}

__device__ __forceinline__ bf16x8 cvt8(float4 lo, float4 hi) {
    bf16x8 r;
    r[0] = (short)f2bf(lo.x); r[1] = (short)f2bf(lo.y);
    r[2] = (short)f2bf(lo.z); r[3] = (short)f2bf(lo.w);
    r[4] = (short)f2bf(hi.x); r[5] = (short)f2bf(hi.y);
    r[6] = (short)f2bf(hi.z); r[7] = (short)f2bf(hi.w);
    return r;
}

// ---------------------------------------------------------------------------
// Fused projection kernel, 512 thr, grid 1024.
//   bid <  512: V projection via bf16 MFMA with IN-BLOCK x transpose
//               (LDS fp32 tile -> bf16 LDS). Block = (b, nb): n-range 64,
//               e-range 256 across 8 waves (2 n-half x 4 e-quarter).
//               lid: b = (lid&7) + 8*(lid>>7); nb = (lid>>3)&15.
//   bid >= 512: q,k projection, bit-exact ascending-c fmaf chain; w rows
//               read DIRECTLY (4 uniform s_loads per c). Two 256-thr
//               sub-blocks (sub = t>>8) covering nt = ntp*2 + sub.
//               lid: b = (lid&7) + 8*(lid>>7); rg = (lid>>3)&7; ntp=(lid>>6)&1.
// ---------------------------------------------------------------------------
__global__ __launch_bounds__(512) void projall_kernel(
    const float* __restrict__ x,
    const float* __restrict__ wq, const float* __restrict__ bq,
    const float* __restrict__ wk, const float* __restrict__ bk,
    const float* __restrict__ wv, const float* __restrict__ bv,
    float* __restrict__ qk, float* __restrict__ vt)
{
    __shared__ __align__(16) float tl[64][65];             // 16.6 KB
    __shared__ __align__(16) unsigned short xbf[64][264];  // 33.8 KB (row 528B, 16B-aligned)

    const int bid = blockIdx.x;
    const int t = threadIdx.x;
    const int lane = t & 63;

    if (bid < 512) {
        // ---------------- V path: in-block transpose + bf16 MFMA ----------
        const int lid = bid;
        const int b  = (lid & 7) + 8 * (lid >> 7);
        const int nb = (lid >> 3) & 15;
        const int n0 = nb * 64;

        const float* xb = x + (size_t)b * C_ * N_;
        for (int ct = 0; ct < 4; ++ct) {
            const int c0 = ct * 64;
            #pragma unroll
            for (int p = 0; p < 2; ++p) {
                const int cl = (t >> 4) + p * 32;
                const int nl = (t & 15) * 4;
                *(float4*)&tl[cl][nl] = *(const float4*)&xb[(size_t)(c0 + cl) * N_ + n0 + nl];
            }
            __syncthreads();
            #pragma unroll
            for (int p = 0; p < 2; ++p) {
                const int nl = (t >> 4) + p * 32;
                const int cl4 = (t & 15) * 4;
                ushort4 o;
                o.x = f2bf(tl[cl4 + 0][nl]);
                o.y = f2bf(tl[cl4 + 1][nl]);
                o.z = f2bf(tl[cl4 + 2][nl]);
                o.w = f2bf(tl[cl4 + 3][nl]);
                *(ushort4*)&xbf[nl][c0 + cl4] = o;
            }
            __syncthreads();
        }

        const int w    = t >> 6;      // 0..7
        const int wn   = w & 1;       // n half (32)
        const int we   = w >> 1;      // e quarter (64)
        const int l16  = lane & 15;
        const int koff = 8 * (lane >> 4);

        f32x4 acc[2][4];
        #pragma unroll
        for (int i = 0; i < 2; ++i)
            #pragma unroll
            for (int j = 0; j < 4; ++j) acc[i][j] = (f32x4)(0.f);

        #pragma unroll
        for (int kk = 0; kk < 8; ++kk) {
            const int c0k = kk * 32;
            const bf16x8 b0 = *(const bf16x8*)&xbf[wn * 32 + l16][koff + c0k];
            const bf16x8 b1 = *(const bf16x8*)&xbf[wn * 32 + 16 + l16][koff + c0k];
            #pragma unroll
            for (int et = 0; et < 4; ++et) {
                const float* wr = wv + (size_t)(we * 64 + et * 16 + l16) * C_ + koff + c0k;
                const float4 lo = *(const float4*)wr;
                const float4 hi = *(const float4*)(wr + 4);
                const bf16x8 a = cvt8(lo, hi);
                acc[0][et] = __builtin_amdgcn_mfma_f32_16x16x32_bf16(a, b0, acc[0][et], 0, 0, 0);
                acc[1][et] = __builtin_amdgcn_mfma_f32_16x16x32_bf16(a, b1, acc[1][et], 0, 0, 0);
            }
        }

        const int col  = lane & 15;
        const int row0 = (lane >> 4) * 4;
        #pragma unroll
        for (int et = 0; et < 4; ++et) {
            const int e0 = we * 64 + et * 16 + row0;
            const float4 bvv = *(const float4*)&bv[e0];
            #pragma unroll
            for (int nt = 0; nt < 2; ++nt) {
                const int n = n0 + wn * 32 + nt * 16 + col;
                float4 o;
                o.x = acc[nt][et][0] + bvv.x; o.y = acc[nt][et][1] + bvv.y;
                o.z = acc[nt][et][2] + bvv.z; o.w = acc[nt][et][3] + bvv.w;
                *(float4*)&vt[((size_t)b * N_ + n) * C_ + e0] = o;
            }
        }
    } else {
        // ---------------- q,k path: bit-exact fmaf chain, direct w reads ----
        const int lid = bid - 512;
        const int b   = (lid & 7) + 8 * (lid >> 7);
        const int rg  = (lid >> 3) & 7;
        const int ntp = (lid >> 6) & 1;
        const int sub = __builtin_amdgcn_readfirstlane(t >> 8);       // 0/1
        const int wu  = __builtin_amdgcn_readfirstlane((t >> 6) & 3); // 0..3
        const int nt  = ntp * 2 + sub;
        const int r0 = rg * 16;
        const int n0 = nt * 256;
        const int rw = r0 + wu * 4;    // wave's first row (uniform), < 128

        const float* w0p = (rw < 64) ? (wq + (size_t)rw * C_) : (wk + (size_t)(rw - 64) * C_);
        const float* w1p = w0p + C_;
        const float* w2p = w0p + 2 * C_;
        const float* w3p = w0p + 3 * C_;

        float acc[4][4];
        #pragma unroll
        for (int i = 0; i < 4; ++i)
            #pragma unroll
            for (int j = 0; j < 4; ++j) acc[i][j] = 0.f;

        const float* xp = x + (size_t)b * C_ * N_ + n0 + lane * 4;

        #pragma unroll 8
        for (int c = 0; c < C_; ++c) {
            const float4 xv = *(const float4*)(xp + (size_t)c * N_);
            const float wv4[4] = { w0p[c], w1p[c], w2p[c], w3p[c] };   // uniform s_loads
            #pragma unroll
            for (int i = 0; i < 4; ++i) {
                acc[i][0] = fmaf(wv4[i], xv.x, acc[i][0]);
                acc[i][1] = fmaf(wv4[i], xv.y, acc[i][1]);
                acc[i][2] = fmaf(wv4[i], xv.z, acc[i][2]);
                acc[i][3] = fmaf(wv4[i], xv.w, acc[i][3]);
            }
        }

        #pragma unroll
        for (int i = 0; i < 4; ++i) {
            const int R = rw + i;
            const float bb = (R < 64) ? bq[R] : bk[R - 64];
            float4 o; o.x = acc[i][0]+bb; o.y = acc[i][1]+bb; o.z = acc[i][2]+bb; o.w = acc[i][3]+bb;
            *(float4*)&qk[((size_t)b * 128 + R) * N_ + n0 + lane * 4] = o;
        }
    }
}

// ---------------------------------------------------------------------------
// Attention (r21 verbatim). Sim (scalar fmaf) + stage A (DPP threshold,
// cap-48 compaction + exact fallback) + stage B split-half DPP extraction +
// decode/softmax/batched gathers + residual write.
// ---------------------------------------------------------------------------
__global__ __launch_bounds__(512) void attn_kernel(
    const float* __restrict__ x,
    const float* __restrict__ qk,
    const float* __restrict__ vt,
    const float* __restrict__ scale,
    float* __restrict__ out)
{
    const int lid = blockIdx.x;
    const int b  = (lid & 7) + 8 * (lid >> 9);
    const int n0 = ((lid >> 3) & 63) * 16;
    const int t  = threadIdx.x;
    const int lane = t & 63;
    const int w  = t >> 6;
    const int ms = w & 3;
    const int rg = __builtin_amdgcn_readfirstlane(t >> 8);

    __shared__ unsigned long long cand[16][196];
    __shared__ int   ccnt[16][4];

    const int m_base = ms * 256 + lane * 4;

    float a0[8], a1[8], a2[8], a3[8];
    #pragma unroll
    for (int r = 0; r < 8; ++r) { a0[r]=0.f; a1[r]=0.f; a2[r]=0.f; a3[r]=0.f; }

    const float* kb = qk + ((size_t)b * 128 + 64) * N_ + m_base;
    const float* qb = qk + (size_t)b * 128 * N_ + n0 + rg * 8;

    #pragma unroll 2
    for (int d0 = 0; d0 < D_; d0 += 4) {
        const float4 k0 = *(const float4*)&kb[(size_t)(d0+0) * N_];
        const float4 k1 = *(const float4*)&kb[(size_t)(d0+1) * N_];
        const float4 k2 = *(const float4*)&kb[(size_t)(d0+2) * N_];
        const float4 k3 = *(const float4*)&kb[(size_t)(d0+3) * N_];

        float qs[4][8];
        #pragma unroll
        for (int dd = 0; dd < 4; ++dd) {
            #pragma unroll
            for (int rq = 0; rq < 2; ++rq) {
                const float4 qv = *(const float4*)&qb[(size_t)(d0 + dd) * N_ + rq * 4];
                qs[dd][rq*4+0] = qv.x; qs[dd][rq*4+1] = qv.y;
                qs[dd][rq*4+2] = qv.z; qs[dd][rq*4+3] = qv.w;
            }
        }

        #pragma unroll
        for (int r = 0; r < 8; ++r) {
            a0[r] = fmaf(qs[0][r], k0.x, a0[r]); a0[r] = fmaf(qs[1][r], k1.x, a0[r]);
            a0[r] = fmaf(qs[2][r], k2.x, a0[r]); a0[r] = fmaf(qs[3][r], k3.x, a0[r]);
            a1[r] = fmaf(qs[0][r], k0.y, a1[r]); a1[r] = fmaf(qs[1][r], k1.y, a1[r]);
            a1[r] = fmaf(qs[2][r], k2.y, a1[r]); a1[r] = fmaf(qs[3][r], k3.y, a1[r]);
            a2[r] = fmaf(qs[0][r], k0.z, a2[r]); a2[r] = fmaf(qs[1][r], k1.z, a2[r]);
            a2[r] = fmaf(qs[2][r], k2.z, a2[r]); a2[r] = fmaf(qs[3][r], k3.z, a2[r]);
            a3[r] = fmaf(qs[0][r], k0.w, a3[r]); a3[r] = fmaf(qs[1][r], k1.w, a3[r]);
            a3[r] = fmaf(qs[2][r], k2.w, a3[r]); a3[r] = fmaf(qs[3][r], k3.w, a3[r]);
        }
    }

    // ---- stage A: per-slice threshold filter + compaction (exact superset) ----
    const unsigned long long lt = (1ull << lane) - 1ull;
    #pragma unroll
    for (int r = 0; r < 8; ++r) {
        const int ri = rg * 8 + r;
        const int nrow = n0 + ri;
        float t0 = a0[r], t1 = a1[r], t2 = a2[r], t3 = a3[r];
        const int dj = nrow - m_base;
        if      (dj == 0) t0 = -1.0e9f;
        else if (dj == 1) t1 = -1.0e9f;
        else if (dj == 2) t2 = -1.0e9f;
        else if (dj == 3) t3 = -1.0e9f;

        float lm = fmaxf(fmaxf(t0, t1), fmaxf(t2, t3));
        lm = fmaxf(lm, dpp_mov_f<DPP_QUAD_XOR1>(lm));
        lm = fmaxf(lm, dpp_mov_f<DPP_QUAD_XOR2>(lm));
        lm = fmaxf(lm, dpp_mov_f<DPP_HALF_MIRROR>(lm));
        float Th = fminf(lm, dpp_mov_f<DPP_ROW_ROR8>(lm));
        Th = fminf(Th, __shfl_xor(Th, 16));
        Th = fminf(Th, __shfl_xor(Th, 32));

        int cnt = 0;
        {
            const bool p = (t0 >= Th);
            const unsigned long long msk = __ballot(p);
            const int pos = cnt + (int)__popcll(msk & lt);
            if (p && pos < 48) cand[ri][ms * 49 + pos] = pack_key(t0, m_base + 0);
            cnt += (int)__popcll(msk);
        }
        {
            const bool p = (t1 >= Th);
            const unsigned long long msk = __ballot(p);
            const int pos = cnt + (int)__popcll(msk & lt);
            if (p && pos < 48) cand[ri][ms * 49 + pos] = pack_key(t1, m_base + 1);
            cnt += (int)__popcll(msk);
        }
        {
            const bool p = (t2 >= Th);
            const unsigned long long msk = __ballot(p);
            const int pos = cnt + (int)__popcll(msk & lt);
            if (p && pos < 48) cand[ri][ms * 49 + pos] = pack_key(t2, m_base + 2);
            cnt += (int)__popcll(msk);
        }
        {
            const bool p = (t3 >= Th);
            const unsigned long long msk = __ballot(p);
            const int pos = cnt + (int)__popcll(msk & lt);
            if (p && pos < 48) cand[ri][ms * 49 + pos] = pack_key(t3, m_base + 3);
            cnt += (int)__popcll(msk);
        }

        if (cnt > 48) {   // exact fallback: slice top-8 via 8 extraction rounds
            unsigned long long K0 = pack_key(t0, m_base + 0);
            unsigned long long K1 = pack_key(t1, m_base + 1);
            unsigned long long K2 = pack_key(t2, m_base + 2);
            unsigned long long K3 = pack_key(t3, m_base + 3);
            #pragma unroll 1
            for (int round = 0; round < 8; ++round) {
                unsigned long long kl = K0 > K1 ? K0 : K1;
                kl = K2 > kl ? K2 : kl;
                kl = K3 > kl ? K3 : kl;
                #pragma unroll
                for (int off = 32; off >= 1; off >>= 1) {
                    const unsigned long long ks = __shfl_xor(kl, off);
                    if (ks > kl) kl = ks;
                }
                if (lane == 0) cand[ri][ms * 49 + round] = kl;
                if      (K0 == kl) K0 = 0ull;
                else if (K1 == kl) K1 = 0ull;
                else if (K2 == kl) K2 = 0ull;
                else if (K3 == kl) K3 = 0ull;
            }
            cnt = 8;
        }
        if (lane == 0) ccnt[ri][ms] = cnt;
    }
    __syncthreads();

    // ---- stage B: split-half extraction (2 rows concurrently per wave) ----
    {
        const int half = lane >> 5;          // 0 -> row w*2, 1 -> row w*2+1
        const int r    = w * 2 + half;
        const int l5   = lane & 31;

        unsigned long long k[6];
        #pragma unroll
        for (int s = 0; s < 4; ++s)
            k[s] = (l5 < ccnt[r][s]) ? cand[r][s * 49 + l5] : 0ull;
        #pragma unroll
        for (int j = 0; j < 2; ++j) {
            const int g   = l5 + 32 * j;     // 0..63
            const int s   = g >> 4;          // 0..3
            const int pos = 32 + (g & 15);   // 32..47
            k[4 + j] = (pos < ccnt[r][s]) ? cand[r][s * 49 + pos] : 0ull;
        }

        #pragma unroll 1
        for (int round = 0; round < 8; ++round) {
            unsigned long long km = k[0];
            #pragma unroll
            for (int q = 1; q < 6; ++q) km = k[q] > km ? k[q] : km;
            km = dpp_max_u64<DPP_QUAD_XOR1>(km);
            km = dpp_max_u64<DPP_QUAD_XOR2>(km);
            km = dpp_max_u64<DPP_HALF_MIRROR>(km);
            km = dpp_max_u64<DPP_ROW_ROR8>(km);
            { const unsigned long long p = __shfl_xor(km, 16); km = p > km ? p : km; }
            if (l5 == 0) cand[r][188 + round] = km;   // winners, clear of union
            #pragma unroll
            for (int q = 0; q < 6; ++q) if (k[q] == km) k[q] = 0ull;
        }
    }

    // ---- decode winners + softmax + batched V gathers (all 64 lanes/row) ----
    const float* vtb = vt + (size_t)b * N_ * C_;
    #pragma unroll 1
    for (int rr = 0; rr < 2; ++rr) {
        const int r = w * 2 + rr;
        float ev[8]; unsigned int mi[8];
        float S = 0.f, vmax = 0.f;
        #pragma unroll
        for (int j = 0; j < 8; ++j) {
            const unsigned long long km = cand[r][188 + j];
            const unsigned int mono = (unsigned int)(km >> 10);
            mi[j] = 1023u - ((unsigned int)km & 1023u);
            const unsigned int bits = (mono & 0x80000000u) ? (mono & 0x7FFFFFFFu) : ~mono;
            const float vraw = __uint_as_float(bits);
            if (j == 0) vmax = vraw;
            const float e = __expf((vraw - vmax) * 0.125f);
            S += e;
            ev[j] = e;
        }

        float4 o = make_float4(0.f, 0.f, 0.f, 0.f);
        #pragma unroll
        for (int j = 0; j < 8; ++j) {
            const float4 vv = *(const float4*)&vtb[(size_t)mi[j] * C_ + lane * 4];
            o.x += ev[j] * vv.x; o.y += ev[j] * vv.y;
            o.z += ev[j] * vv.z; o.w += ev[j] * vv.w;
        }
        const float inv = 1.f / S;
        float* orow = (float*)&cand[r][0];   // union: out row over cand row r
        *(float4*)&orow[lane * 4] = make_float4(o.x*inv, o.y*inv, o.z*inv, o.w*inv);
    }
    __syncthreads();

    // ---- residual + (b, c, n) write ----
    const float sc = scale[0];
    const float* xb = x + (size_t)b * C_ * N_;
    float* ob = out + (size_t)b * C_ * N_;
    const int nl = t & 15;
    const int cg = t >> 4;
    const float* orow = (const float*)&cand[nl][0];
    #pragma unroll
    for (int i = 0; i < 8; ++i) {
        const int cc = i * 32 + cg;
        const size_t gi = (size_t)cc * N_ + n0 + nl;
        ob[gi] = xb[gi] + sc * orow[cc];
    }
}

extern "C" void kernel_launch(void* const* d_in, const int* in_sizes, int n_in,
                              void* d_out, int out_size, void* d_ws, size_t ws_size,
                              hipStream_t stream) {
    const float* x     = (const float*)d_in[0];
    const float* wq    = (const float*)d_in[1];
    const float* bq    = (const float*)d_in[2];
    const float* wk    = (const float*)d_in[3];
    const float* bk    = (const float*)d_in[4];
    const float* wv    = (const float*)d_in[5];
    const float* bv    = (const float*)d_in[6];
    const float* scale = (const float*)d_in[7];
    float* out = (float*)d_out;

    float* qk = (float*)d_ws;                    // (b,128,n) fp32 = 16.78 MB
    float* vt = qk + (size_t)B_ * 128 * N_;      // (b,n,c)  fp32 = 33.55 MB

    projall_kernel<<<dim3(1024), 512, 0, stream>>>(x, wq, bq, wk, bk, wv, bv, qk, vt);
    attn_kernel<<<dim3(2048), 512, 0, stream>>>(x, qk, vt, scale, out);
}

// Round 23
// 165.804 us; speedup vs baseline: 1.4299x; 1.0203x over previous
//
#include <hip/hip_runtime.h>
#include <hip/hip_bf16.h>

#define B_ 32
#define C_ 256
#define N_ 1024
#define D_ 64

typedef __attribute__((ext_vector_type(8))) short bf16x8;
typedef __attribute__((ext_vector_type(4))) float f32x4;

// key = (monotone(v) << 10) | (1023 - m): larger key <=> larger v, tie -> smaller m.
__device__ __forceinline__ unsigned long long pack_key(float v, int m) {
    const unsigned int bits = __float_as_uint(v);
    const unsigned int mono = (bits & 0x80000000u) ? ~bits : (bits | 0x80000000u);
    return ((unsigned long long)mono << 10) | (unsigned long long)(1023 - m);
}

// DPP cross-lane move (VALU pipe, not DS). ctrl must be an immediate -> template.
template <int CTRL>
__device__ __forceinline__ float dpp_mov_f(float x) {
    return __int_as_float(__builtin_amdgcn_update_dpp(
        0, __float_as_int(x), CTRL, 0xF, 0xF, true));
}
#define DPP_QUAD_XOR1   0xB1
#define DPP_QUAD_XOR2   0x4E
#define DPP_HALF_MIRROR 0x141
#define DPP_ROW_ROR8    0x128

// u64 max with DPP-permuted partner (xor1/2/4/8 patterns; VALU only).
template <int CTRL>
__device__ __forceinline__ unsigned long long dpp_max_u64(unsigned long long k) {
    const unsigned int lo = (unsigned int)k;
    const unsigned int hi = (unsigned int)(k >> 32);
    const unsigned int plo = (unsigned int)__builtin_amdgcn_update_dpp(0, (int)lo, CTRL, 0xF, 0xF, true);
    const unsigned int phi = (unsigned int)__builtin_amdgcn_update_dpp(0, (int)hi, CTRL, 0xF, 0xF, true);
    const unsigned long long p = ((unsigned long long)phi << 32) | plo;
    return p > k ? p : k;
}

__device__ __forceinline__ unsigned short f2bf(float f) {
    __hip_bfloat16 h = __float2bfloat16(f);
    return *(unsigned short*)&h;
}

__device__ __forceinline__ bf16x8 cvt8(float4 lo, float4 hi) {
    bf16x8 r;
    r[0] = (short)f2bf(lo.x); r[1] = (short)f2bf(lo.y);
    r[2] = (short)f2bf(lo.z); r[3] = (short)f2bf(lo.w);
    r[4] = (short)f2bf(hi.x); r[5] = (short)f2bf(hi.y);
    r[6] = (short)f2bf(hi.z); r[7] = (short)f2bf(hi.w);
    return r;
}

// ---------------------------------------------------------------------------
// Fused projection kernel (r22 verbatim), 512 thr, grid 1024.
//   bid <  512: V projection via bf16 MFMA with in-block x transpose.
//   bid >= 512: q,k projection, bit-exact ascending-c fmaf chain.
// ---------------------------------------------------------------------------
__global__ __launch_bounds__(512) void projall_kernel(
    const float* __restrict__ x,
    const float* __restrict__ wq, const float* __restrict__ bq,
    const float* __restrict__ wk, const float* __restrict__ bk,
    const float* __restrict__ wv, const float* __restrict__ bv,
    float* __restrict__ qk, float* __restrict__ vt)
{
    __shared__ __align__(16) float tl[64][65];             // 16.6 KB
    __shared__ __align__(16) unsigned short xbf[64][264];  // 33.8 KB

    const int bid = blockIdx.x;
    const int t = threadIdx.x;
    const int lane = t & 63;

    if (bid < 512) {
        const int lid = bid;
        const int b  = (lid & 7) + 8 * (lid >> 7);
        const int nb = (lid >> 3) & 15;
        const int n0 = nb * 64;

        const float* xb = x + (size_t)b * C_ * N_;
        for (int ct = 0; ct < 4; ++ct) {
            const int c0 = ct * 64;
            #pragma unroll
            for (int p = 0; p < 2; ++p) {
                const int cl = (t >> 4) + p * 32;
                const int nl = (t & 15) * 4;
                *(float4*)&tl[cl][nl] = *(const float4*)&xb[(size_t)(c0 + cl) * N_ + n0 + nl];
            }
            __syncthreads();
            #pragma unroll
            for (int p = 0; p < 2; ++p) {
                const int nl = (t >> 4) + p * 32;
                const int cl4 = (t & 15) * 4;
                ushort4 o;
                o.x = f2bf(tl[cl4 + 0][nl]);
                o.y = f2bf(tl[cl4 + 1][nl]);
                o.z = f2bf(tl[cl4 + 2][nl]);
                o.w = f2bf(tl[cl4 + 3][nl]);
                *(ushort4*)&xbf[nl][c0 + cl4] = o;
            }
            __syncthreads();
        }

        const int w    = t >> 6;
        const int wn   = w & 1;
        const int we   = w >> 1;
        const int l16  = lane & 15;
        const int koff = 8 * (lane >> 4);

        f32x4 acc[2][4];
        #pragma unroll
        for (int i = 0; i < 2; ++i)
            #pragma unroll
            for (int j = 0; j < 4; ++j) acc[i][j] = (f32x4)(0.f);

        #pragma unroll
        for (int kk = 0; kk < 8; ++kk) {
            const int c0k = kk * 32;
            const bf16x8 b0 = *(const bf16x8*)&xbf[wn * 32 + l16][koff + c0k];
            const bf16x8 b1 = *(const bf16x8*)&xbf[wn * 32 + 16 + l16][koff + c0k];
            #pragma unroll
            for (int et = 0; et < 4; ++et) {
                const float* wr = wv + (size_t)(we * 64 + et * 16 + l16) * C_ + koff + c0k;
                const float4 lo = *(const float4*)wr;
                const float4 hi = *(const float4*)(wr + 4);
                const bf16x8 a = cvt8(lo, hi);
                acc[0][et] = __builtin_amdgcn_mfma_f32_16x16x32_bf16(a, b0, acc[0][et], 0, 0, 0);
                acc[1][et] = __builtin_amdgcn_mfma_f32_16x16x32_bf16(a, b1, acc[1][et], 0, 0, 0);
            }
        }

        const int col  = lane & 15;
        const int row0 = (lane >> 4) * 4;
        #pragma unroll
        for (int et = 0; et < 4; ++et) {
            const int e0 = we * 64 + et * 16 + row0;
            const float4 bvv = *(const float4*)&bv[e0];
            #pragma unroll
            for (int nt = 0; nt < 2; ++nt) {
                const int n = n0 + wn * 32 + nt * 16 + col;
                float4 o;
                o.x = acc[nt][et][0] + bvv.x; o.y = acc[nt][et][1] + bvv.y;
                o.z = acc[nt][et][2] + bvv.z; o.w = acc[nt][et][3] + bvv.w;
                *(float4*)&vt[((size_t)b * N_ + n) * C_ + e0] = o;
            }
        }
    } else {
        const int lid = bid - 512;
        const int b   = (lid & 7) + 8 * (lid >> 7);
        const int rg  = (lid >> 3) & 7;
        const int ntp = (lid >> 6) & 1;
        const int sub = __builtin_amdgcn_readfirstlane(t >> 8);
        const int wu  = __builtin_amdgcn_readfirstlane((t >> 6) & 3);
        const int nt  = ntp * 2 + sub;
        const int r0 = rg * 16;
        const int n0 = nt * 256;
        const int rw = r0 + wu * 4;

        const float* w0p = (rw < 64) ? (wq + (size_t)rw * C_) : (wk + (size_t)(rw - 64) * C_);
        const float* w1p = w0p + C_;
        const float* w2p = w0p + 2 * C_;
        const float* w3p = w0p + 3 * C_;

        float acc[4][4];
        #pragma unroll
        for (int i = 0; i < 4; ++i)
            #pragma unroll
            for (int j = 0; j < 4; ++j) acc[i][j] = 0.f;

        const float* xp = x + (size_t)b * C_ * N_ + n0 + lane * 4;

        #pragma unroll 8
        for (int c = 0; c < C_; ++c) {
            const float4 xv = *(const float4*)(xp + (size_t)c * N_);
            const float wv4[4] = { w0p[c], w1p[c], w2p[c], w3p[c] };
            #pragma unroll
            for (int i = 0; i < 4; ++i) {
                acc[i][0] = fmaf(wv4[i], xv.x, acc[i][0]);
                acc[i][1] = fmaf(wv4[i], xv.y, acc[i][1]);
                acc[i][2] = fmaf(wv4[i], xv.z, acc[i][2]);
                acc[i][3] = fmaf(wv4[i], xv.w, acc[i][3]);
            }
        }

        #pragma unroll
        for (int i = 0; i < 4; ++i) {
            const int R = rw + i;
            const float bb = (R < 64) ? bq[R] : bk[R - 64];
            float4 o; o.x = acc[i][0]+bb; o.y = acc[i][1]+bb; o.z = acc[i][2]+bb; o.w = acc[i][3]+bb;
            *(float4*)&qk[((size_t)b * 128 + R) * N_ + n0 + lane * 4] = o;
        }
    }
}

// ---------------------------------------------------------------------------
// Attention: 8 rows x 4 waves (256 thr), grid 4096. Per-wave program is
// IDENTICAL to r22 (8 rows x 256-m slice each); only the block tiling is
// halved for finer residency granularity (12.7 KB LDS, 4-wave barriers).
// lid = (b&7) + 8*ntile + 1024*(b>>3); ntile 0..127 (8 rows each).
// ---------------------------------------------------------------------------
__global__ __launch_bounds__(256) void attn_kernel(
    const float* __restrict__ x,
    const float* __restrict__ qk,
    const float* __restrict__ vt,
    const float* __restrict__ scale,
    float* __restrict__ out)
{
    const int lid = blockIdx.x;
    const int b  = (lid & 7) + 8 * (lid >> 10);
    const int n0 = ((lid >> 3) & 127) * 8;
    const int t  = threadIdx.x;
    const int lane = t & 63;
    const int w  = t >> 6;          // 0..3
    const int ms = w;               // m-slice

    __shared__ unsigned long long cand[8][196];   // 12544 B
    __shared__ int   ccnt[8][4];                  //   128 B

    const int m_base = ms * 256 + lane * 4;

    float a0[8], a1[8], a2[8], a3[8];
    #pragma unroll
    for (int r = 0; r < 8; ++r) { a0[r]=0.f; a1[r]=0.f; a2[r]=0.f; a3[r]=0.f; }

    const float* kb = qk + ((size_t)b * 128 + 64) * N_ + m_base;
    const float* qb = qk + (size_t)b * 128 * N_ + n0;

    #pragma unroll 2
    for (int d0 = 0; d0 < D_; d0 += 4) {
        const float4 k0 = *(const float4*)&kb[(size_t)(d0+0) * N_];
        const float4 k1 = *(const float4*)&kb[(size_t)(d0+1) * N_];
        const float4 k2 = *(const float4*)&kb[(size_t)(d0+2) * N_];
        const float4 k3 = *(const float4*)&kb[(size_t)(d0+3) * N_];

        float qs[4][8];
        #pragma unroll
        for (int dd = 0; dd < 4; ++dd) {
            #pragma unroll
            for (int rq = 0; rq < 2; ++rq) {
                const float4 qv = *(const float4*)&qb[(size_t)(d0 + dd) * N_ + rq * 4];
                qs[dd][rq*4+0] = qv.x; qs[dd][rq*4+1] = qv.y;
                qs[dd][rq*4+2] = qv.z; qs[dd][rq*4+3] = qv.w;
            }
        }

        #pragma unroll
        for (int r = 0; r < 8; ++r) {
            a0[r] = fmaf(qs[0][r], k0.x, a0[r]); a0[r] = fmaf(qs[1][r], k1.x, a0[r]);
            a0[r] = fmaf(qs[2][r], k2.x, a0[r]); a0[r] = fmaf(qs[3][r], k3.x, a0[r]);
            a1[r] = fmaf(qs[0][r], k0.y, a1[r]); a1[r] = fmaf(qs[1][r], k1.y, a1[r]);
            a1[r] = fmaf(qs[2][r], k2.y, a1[r]); a1[r] = fmaf(qs[3][r], k3.y, a1[r]);
            a2[r] = fmaf(qs[0][r], k0.z, a2[r]); a2[r] = fmaf(qs[1][r], k1.z, a2[r]);
            a2[r] = fmaf(qs[2][r], k2.z, a2[r]); a2[r] = fmaf(qs[3][r], k3.z, a2[r]);
            a3[r] = fmaf(qs[0][r], k0.w, a3[r]); a3[r] = fmaf(qs[1][r], k1.w, a3[r]);
            a3[r] = fmaf(qs[2][r], k2.w, a3[r]); a3[r] = fmaf(qs[3][r], k3.w, a3[r]);
        }
    }

    // ---- stage A: per-slice threshold filter + compaction (exact superset) ----
    const unsigned long long lt = (1ull << lane) - 1ull;
    #pragma unroll
    for (int r = 0; r < 8; ++r) {
        const int nrow = n0 + r;
        float t0 = a0[r], t1 = a1[r], t2 = a2[r], t3 = a3[r];
        const int dj = nrow - m_base;
        if      (dj == 0) t0 = -1.0e9f;
        else if (dj == 1) t1 = -1.0e9f;
        else if (dj == 2) t2 = -1.0e9f;
        else if (dj == 3) t3 = -1.0e9f;

        float lm = fmaxf(fmaxf(t0, t1), fmaxf(t2, t3));
        lm = fmaxf(lm, dpp_mov_f<DPP_QUAD_XOR1>(lm));
        lm = fmaxf(lm, dpp_mov_f<DPP_QUAD_XOR2>(lm));
        lm = fmaxf(lm, dpp_mov_f<DPP_HALF_MIRROR>(lm));
        float Th = fminf(lm, dpp_mov_f<DPP_ROW_ROR8>(lm));
        Th = fminf(Th, __shfl_xor(Th, 16));
        Th = fminf(Th, __shfl_xor(Th, 32));

        int cnt = 0;
        {
            const bool p = (t0 >= Th);
            const unsigned long long msk = __ballot(p);
            const int pos = cnt + (int)__popcll(msk & lt);
            if (p && pos < 48) cand[r][ms * 49 + pos] = pack_key(t0, m_base + 0);
            cnt += (int)__popcll(msk);
        }
        {
            const bool p = (t1 >= Th);
            const unsigned long long msk = __ballot(p);
            const int pos = cnt + (int)__popcll(msk & lt);
            if (p && pos < 48) cand[r][ms * 49 + pos] = pack_key(t1, m_base + 1);
            cnt += (int)__popcll(msk);
        }
        {
            const bool p = (t2 >= Th);
            const unsigned long long msk = __ballot(p);
            const int pos = cnt + (int)__popcll(msk & lt);
            if (p && pos < 48) cand[r][ms * 49 + pos] = pack_key(t2, m_base + 2);
            cnt += (int)__popcll(msk);
        }
        {
            const bool p = (t3 >= Th);
            const unsigned long long msk = __ballot(p);
            const int pos = cnt + (int)__popcll(msk & lt);
            if (p && pos < 48) cand[r][ms * 49 + pos] = pack_key(t3, m_base + 3);
            cnt += (int)__popcll(msk);
        }

        if (cnt > 48) {   // exact fallback: slice top-8 via 8 extraction rounds
            unsigned long long K0 = pack_key(t0, m_base + 0);
            unsigned long long K1 = pack_key(t1, m_base + 1);
            unsigned long long K2 = pack_key(t2, m_base + 2);
            unsigned long long K3 = pack_key(t3, m_base + 3);
            #pragma unroll 1
            for (int round = 0; round < 8; ++round) {
                unsigned long long kl = K0 > K1 ? K0 : K1;
                kl = K2 > kl ? K2 : kl;
                kl = K3 > kl ? K3 : kl;
                #pragma unroll
                for (int off = 32; off >= 1; off >>= 1) {
                    const unsigned long long ks = __shfl_xor(kl, off);
                    if (ks > kl) kl = ks;
                }
                if (lane == 0) cand[r][ms * 49 + round] = kl;
                if      (K0 == kl) K0 = 0ull;
                else if (K1 == kl) K1 = 0ull;
                else if (K2 == kl) K2 = 0ull;
                else if (K3 == kl) K3 = 0ull;
            }
            cnt = 8;
        }
        if (lane == 0) ccnt[r][ms] = cnt;
    }
    __syncthreads();

    // ---- stage B: split-half extraction (2 rows concurrently per wave) ----
    {
        const int half = lane >> 5;          // 0 -> row w*2, 1 -> row w*2+1
        const int r    = w * 2 + half;
        const int l5   = lane & 31;

        unsigned long long k[6];
        #pragma unroll
        for (int s = 0; s < 4; ++s)
            k[s] = (l5 < ccnt[r][s]) ? cand[r][s * 49 + l5] : 0ull;
        #pragma unroll
        for (int j = 0; j < 2; ++j) {
            const int g   = l5 + 32 * j;     // 0..63
            const int s   = g >> 4;          // 0..3
            const int pos = 32 + (g & 15);   // 32..47
            k[4 + j] = (pos < ccnt[r][s]) ? cand[r][s * 49 + pos] : 0ull;
        }

        #pragma unroll 1
        for (int round = 0; round < 8; ++round) {
            unsigned long long km = k[0];
            #pragma unroll
            for (int q = 1; q < 6; ++q) km = k[q] > km ? k[q] : km;
            km = dpp_max_u64<DPP_QUAD_XOR1>(km);
            km = dpp_max_u64<DPP_QUAD_XOR2>(km);
            km = dpp_max_u64<DPP_HALF_MIRROR>(km);
            km = dpp_max_u64<DPP_ROW_ROR8>(km);
            { const unsigned long long p = __shfl_xor(km, 16); km = p > km ? p : km; }
            if (l5 == 0) cand[r][188 + round] = km;   // winners, clear of union
            #pragma unroll
            for (int q = 0; q < 6; ++q) if (k[q] == km) k[q] = 0ull;
        }
    }

    // ---- decode winners + softmax + batched V gathers (all 64 lanes/row) ----
    const float* vtb = vt + (size_t)b * N_ * C_;
    #pragma unroll 1
    for (int rr = 0; rr < 2; ++rr) {
        const int r = w * 2 + rr;
        float ev[8]; unsigned int mi[8];
        float S = 0.f, vmax = 0.f;
        #pragma unroll
        for (int j = 0; j < 8; ++j) {
            const unsigned long long km = cand[r][188 + j];
            const unsigned int mono = (unsigned int)(km >> 10);
            mi[j] = 1023u - ((unsigned int)km & 1023u);
            const unsigned int bits = (mono & 0x80000000u) ? (mono & 0x7FFFFFFFu) : ~mono;
            const float vraw = __uint_as_float(bits);
            if (j == 0) vmax = vraw;
            const float e = __expf((vraw - vmax) * 0.125f);
            S += e;
            ev[j] = e;
        }

        float4 o = make_float4(0.f, 0.f, 0.f, 0.f);
        #pragma unroll
        for (int j = 0; j < 8; ++j) {
            const float4 vv = *(const float4*)&vtb[(size_t)mi[j] * C_ + lane * 4];
            o.x += ev[j] * vv.x; o.y += ev[j] * vv.y;
            o.z += ev[j] * vv.z; o.w += ev[j] * vv.w;
        }
        const float inv = 1.f / S;
        float* orow = (float*)&cand[r][0];   // union: out row over cand row r
        *(float4*)&orow[lane * 4] = make_float4(o.x*inv, o.y*inv, o.z*inv, o.w*inv);
    }
    __syncthreads();

    // ---- residual + (b, c, n) write ----
    const float sc = scale[0];
    const float* xb = x + (size_t)b * C_ * N_;
    float* ob = out + (size_t)b * C_ * N_;
    const int nl = t & 7;
    const int cg = t >> 3;               // 0..31
    const float* orow = (const float*)&cand[nl][0];
    #pragma unroll
    for (int i = 0; i < 8; ++i) {
        const int cc = i * 32 + cg;
        const size_t gi = (size_t)cc * N_ + n0 + nl;
        ob[gi] = xb[gi] + sc * orow[cc];
    }
}

extern "C" void kernel_launch(void* const* d_in, const int* in_sizes, int n_in,
                              void* d_out, int out_size, void* d_ws, size_t ws_size,
                              hipStream_t stream) {
    const float* x     = (const float*)d_in[0];
    const float* wq    = (const float*)d_in[1];
    const float* bq    = (const float*)d_in[2];
    const float* wk    = (const float*)d_in[3];
    const float* bk    = (const float*)d_in[4];
    const float* wv    = (const float*)d_in[5];
    const float* bv    = (const float*)d_in[6];
    const float* scale = (const float*)d_in[7];
    float* out = (float*)d_out;

    float* qk = (float*)d_ws;                    // (b,128,n) fp32 = 16.78 MB
    float* vt = qk + (size_t)B_ * 128 * N_;      // (b,n,c)  fp32 = 33.55 MB

    projall_kernel<<<dim3(1024), 512, 0, stream>>>(x, wq, bq, wk, bk, wv, bv, qk, vt);
    attn_kernel<<<dim3(4096), 256, 0, stream>>>(x, qk, vt, scale, out);
}